// Round 5
// baseline (284.513 us; speedup 1.0000x reference)
//
#include <hip/hip_runtime.h>
#include <hip/hip_bf16.h>
#include <math.h>

// GNO stem, round 5 == round 4 resubmitted verbatim (round-4 bench died to an
// infra error: "MI355X container failed twice"; source audited for OOB/LDS/
// graph-capture hazards — none found).
//  - 3 launches (was 5): [pre: weight-transpose + vq + GF, block-range split] ->
//    [main4] -> [fin2]. ~18us fixed cost per launch observed.
//  - main4: h1 split into 2x128-col chunks, L2 accumulates partial-K in VGPR ->
//    LDS 52.7 -> ~36 KB -> 4 blocks/CU (was 3).
//  - gf: self-stages W0 transpose in LDS (no cross-block dep); GF written via LDS
//    tile -> coalesced dwordx4 (was 8B scatter).
//  - fin2: 256-q blocks, LDS transpose -> 16B-contiguous out stores (was 4B scatter).

typedef short bs8 __attribute__((ext_vector_type(8)));
typedef float f4  __attribute__((ext_vector_type(4)));

#define MFMA16 __builtin_amdgcn_mfma_f32_16x16x32_bf16

// ---------- fast-path ws layout (bytes) ----------
#define W1T_OFF    0u          // [256][128] bf16  65536
#define W2T_OFF    65536u      // [128][256] bf16  65536
#define W3T_OFF    131072u     // [128][128] bf16  32768
#define VQ_OFF     163840u     // [4096][128] f32  2097152
#define GF_OFF     2260992u    // [2][32768][128] bf16 16777216
#define ST_OFF     19038208u   // [2][4096][128] f32 4194304
#define CNT_OFF    23232512u   // [8192] f32 32768
#define FAST_NEED  23265280u

// ---------- old-path ws layout ----------
#define OW0AT_OFF   0
#define OW1T_OFF    32768
#define OW2T_OFF    98304
#define OW3T_OFF    163840
#define OSTAGED_OFF 196608
#define OLD_NEED    (196608 + 4194304)

__device__ __forceinline__ short f2bf(float f) {
  unsigned u = __float_as_uint(f);
  return (short)((u + 0x7FFFu + ((u >> 16) & 1u)) >> 16);  // RNE
}
__device__ __forceinline__ float bf2f(short s) {
  return __uint_as_float(((unsigned)(unsigned short)s) << 16);
}
__device__ __forceinline__ unsigned pk2bf(float lo, float hi) {
  __hip_bfloat162 h = __float22bfloat162_rn(float2{lo, hi});  // v_cvt_pk_bf16_f32
  return *reinterpret_cast<unsigned*>(&h);
}
__device__ __forceinline__ float gelu_t(float x) {
  // tanh-gelu: x - x/(1+E), E = 2^(x*(a + a*0.044715*x^2)), a = 2*log2e*0.7978845608
  float t = x * x;
  float z = x * fmaf(0.10294322f, t, 2.3022077f);
  float e = __builtin_exp2f(z);
  float r = __builtin_amdgcn_rcpf(e + 1.0f);
  return fmaf(-r, x, x);
}
__device__ __forceinline__ float gelu_old(float x) {
  float z = 0.7978845608028654f * fmaf(0.044715f * x, x * x, x);
  float e = __expf(2.0f * z);
  return 0.5f * x * (2.0f - 2.0f / (e + 1.0f));
}

// =================== fast path ===================

// pre: blocks [0,320) weight transpose; [320,2368) vq; [2368,2880) GF.
__global__ __launch_bounds__(256, 2) void gno_pre(
    const float* __restrict__ x, const float* __restrict__ gc,
    const float* __restrict__ latg,
    const float* __restrict__ W0, const float* __restrict__ b0,
    const float* __restrict__ W1, const float* __restrict__ W2,
    const float* __restrict__ W3,
    short* __restrict__ W1T, short* __restrict__ W2T, short* __restrict__ W3T,
    float* __restrict__ vqPre, short* __restrict__ GF) {
  __shared__ __align__(16) char smem[45056];
  const int tid = threadIdx.x;
  const int blk = blockIdx.x;

  if (blk < 320) {  // ---- weight transpose: 81920 elements ----
    int g = blk * 256 + tid;
    if (g < 32768) {            // W1T [n=256][k=128]
      int nn = g >> 7, k = g & 127;
      W1T[g] = f2bf(W1[k * 256 + nn]);
    } else if (g < 65536) {     // W2T [n=128][k=256]
      int h = g - 32768, nn = h >> 8, k = h & 255;
      W2T[h] = f2bf(W2[k * 128 + nn]);
    } else {                    // W3T [n=128][k=128]
      int h = g - 65536, nn = h >> 7, k = h & 127;
      W3T[h] = f2bf(W3[k * 128 + nn]);
    }
    return;
  }

  if (blk < 2368) {  // ---- vq: q0 = (blk-320)*2 ; fp32 exact ----
    float* embQ  = (float*)smem;          // [2][96]
    float* latS  = (float*)(smem + 768);  // [2][3]
    float* freqS = (float*)(smem + 800);  // [16]
    const int q0 = (blk - 320) * 2;
    if (tid < 16) freqS[tid] = (float)exp(-(double)tid * (9.210340371976184 / 16.0));
    if (tid < 6) latS[tid] = latg[q0 * 3 + tid];
    __syncthreads();
    if (tid < 192) {
      int qh = tid / 96, c = tid % 96, a = c >> 5, jj = c & 31;
      float ca = latS[qh * 3 + a];
      embQ[qh * 96 + c] = (jj < 16) ? __sinf(ca * freqS[jj]) : __cosf(ca * freqS[jj & 15]);
    }
    __syncthreads();
    const int qh = tid >> 7, o = tid & 127;
    float s = b0[o];
#pragma unroll 4
    for (int j = 0; j < 96; ++j) s = fmaf(embQ[qh * 96 + j], W0[(96 + j) * 128 + o], s);
    vqPre[(q0 + qh) * 128 + o] = s;
    return;
  }

  // ---- GF: n0 = (blk-2368)*64 ----
  short* w0eS  = (short*)smem;             // [128][104]  26624 B (reused as tileS)
  short* embS  = (short*)(smem + 26624);   // [64][104]   13312 B
  float* gcS   = (float*)(smem + 39936);   // [64][3]       768 B
  float* xS    = (float*)(smem + 40704);   // [2][4][64]   2048 B
  float* wfS   = (float*)(smem + 42752);   // [4][128]     2048 B
  float* freqS = (float*)(smem + 44800);   // [16]           64 B
  short* tileS = w0eS;                     // [64][132]   16896 B (after MFMA)

  const int n0 = (blk - 2368) * 64;
  if (tid < 16) freqS[tid] = (float)exp(-(double)tid * (9.210340371976184 / 16.0));
  if (tid < 192) gcS[tid] = gc[n0 * 3 + tid];
#pragma unroll
  for (int u = 0; u < 2; ++u) {
    int slot = tid * 2 + u;  // 512 slots
    int bb = slot >> 8, ch = (slot >> 6) & 3, i = slot & 63;
    int n = n0 + i;
    xS[(bb * 4 + ch) * 64 + i] = x[((bb * 4 + ch) << 15) + ((n & 31) << 10) + (n >> 5)];
    wfS[(slot >> 7) * 128 + (slot & 127)] = W0[(192 + (slot >> 7)) * 128 + (slot & 127)];
  }
  // stage W0[0:96] transposed -> w0eS[f][k], coalesced global reads
  for (int e = tid; e < 12288; e += 256) {
    int k = e >> 7, f = e & 127;
    w0eS[f * 104 + k] = f2bf(W0[e]);
  }
  __syncthreads();
  {  // emb trig
    int rr = tid >> 2, c4 = tid & 3;
#pragma unroll
    for (int c = c4 * 24; c < c4 * 24 + 24; ++c) {
      int a = c >> 5, jj = c & 31;
      float v = (jj < 16) ? __sinf(gcS[rr * 3 + a] * freqS[jj])
                          : __cosf(gcS[rr * 3 + a] * freqS[jj & 15]);
      embS[rr * 104 + c] = f2bf(v);
    }
  }
  __syncthreads();
  const int wid = tid >> 6, lane = tid & 63;
  const int l15 = lane & 15, lg = lane >> 4;
  const int f0 = wid * 32;
  f4 acc[2][4] = {};  // [ftile][ptile]; C: col=point(l15), row=feat(lg*4+i)
#pragma unroll
  for (int ks = 0; ks < 3; ++ks) {
    bs8 Aw[2], Be[4];
#pragma unroll
    for (int ft = 0; ft < 2; ++ft)
      Aw[ft] = *(const bs8*)(w0eS + (f0 + ft * 16 + l15) * 104 + ks * 32 + lg * 8);
#pragma unroll
    for (int pt = 0; pt < 4; ++pt)
      Be[pt] = *(const bs8*)(embS + (pt * 16 + l15) * 104 + ks * 32 + lg * 8);
#pragma unroll
    for (int ft = 0; ft < 2; ++ft)
#pragma unroll
      for (int pt = 0; pt < 4; ++pt)
        acc[ft][pt] = MFMA16(Aw[ft], Be[pt], acc[ft][pt], 0, 0, 0);
  }
  __syncthreads();  // w0eS dead -> tileS reuse safe
#pragma unroll 1
  for (int bb = 0; bb < 2; ++bb) {
#pragma unroll
    for (int ft = 0; ft < 2; ++ft) {
      f4 wf0 = *(const f4*)(wfS + 0 * 128 + f0 + ft * 16 + lg * 4);
      f4 wf1 = *(const f4*)(wfS + 1 * 128 + f0 + ft * 16 + lg * 4);
      f4 wf2 = *(const f4*)(wfS + 2 * 128 + f0 + ft * 16 + lg * 4);
      f4 wf3 = *(const f4*)(wfS + 3 * 128 + f0 + ft * 16 + lg * 4);
#pragma unroll
      for (int pt = 0; pt < 4; ++pt) {
        int p = pt * 16 + l15;
        float x0 = xS[(bb * 4 + 0) * 64 + p], x1 = xS[(bb * 4 + 1) * 64 + p];
        float x2 = xS[(bb * 4 + 2) * 64 + p], x3 = xS[(bb * 4 + 3) * 64 + p];
        float v0 = acc[ft][pt][0] + x0 * wf0[0] + x1 * wf1[0] + x2 * wf2[0] + x3 * wf3[0];
        float v1 = acc[ft][pt][1] + x0 * wf0[1] + x1 * wf1[1] + x2 * wf2[1] + x3 * wf3[1];
        float v2 = acc[ft][pt][2] + x0 * wf0[2] + x1 * wf1[2] + x2 * wf2[2] + x3 * wf3[2];
        float v3 = acc[ft][pt][3] + x0 * wf0[3] + x1 * wf1[3] + x2 * wf2[3] + x3 * wf3[3];
        uint2 pp;
        pp.x = pk2bf(v0, v1);
        pp.y = pk2bf(v2, v3);
        *(uint2*)(tileS + p * 132 + f0 + ft * 16 + lg * 4) = pp;
      }
    }
    __syncthreads();
    {  // coalesced copy-out: 64 rows x 256B
      int row = tid >> 2, c4 = tid & 3;
      const short* src = tileS + row * 132 + c4 * 32;
      short* dst = GF + ((size_t)((bb << 15) + n0 + row)) * 128 + c4 * 32;
      *(uint4*)(dst)      = *(const uint4*)(src);
      *(uint4*)(dst + 8)  = *(const uint4*)(src + 8);
      *(uint4*)(dst + 16) = *(const uint4*)(src + 16);
      *(uint4*)(dst + 24) = *(const uint4*)(src + 24);
    }
    __syncthreads();
  }
}

__device__ __forceinline__ uint4 gelu8(bs8 g, const float* vrow) {
  f4 va = *(const f4*)vrow;
  f4 vb = *(const f4*)(vrow + 4);
  uint4 r;
  r.x = pk2bf(gelu_t(bf2f(g[0]) + va[0]), gelu_t(bf2f(g[1]) + va[1]));
  r.y = pk2bf(gelu_t(bf2f(g[2]) + va[2]), gelu_t(bf2f(g[3]) + va[3]));
  r.z = pk2bf(gelu_t(bf2f(g[4]) + vb[0]), gelu_t(bf2f(g[5]) + vb[1]));
  r.w = pk2bf(gelu_t(bf2f(g[6]) + vb[2]), gelu_t(bf2f(g[7]) + vb[3]));
  return r;
}

// main4: block = (b, 2 q) = 64 rows; 4 waves; h1 in 2x128-col chunks (LDS ~36KB).
__global__ __launch_bounds__(256, 4) void gno_main4(
    const float* __restrict__ gc, const float* __restrict__ latg,
    const int* __restrict__ nidx,
    const float* __restrict__ b1, const float* __restrict__ b2,
    const short* __restrict__ W1T, const short* __restrict__ W2T,
    const float* __restrict__ vqPre, const short* __restrict__ GF,
    float* __restrict__ staged, float* __restrict__ cntG) {
  __shared__ __align__(16) short h0S[64][136];
  __shared__ __align__(16) short h1S[64][136];   // one 128-col chunk of h1
  __shared__ float vqS[2][128];
  __shared__ float maskfS[64];

  const int tid = threadIdx.x;
  const int blk = blockIdx.x;
  const int b = blk >> 11;
  const int q0 = (blk & 2047) * 2;

  vqS[tid >> 7][tid & 127] = vqPre[(q0 + (tid >> 7)) * 128 + (tid & 127)];

  const int r = tid >> 2, seg = tid & 3;
  const int qh = r >> 5;
  const int n = nidx[(q0 + qh) * 32 + (r & 31)];
  const bs8* gp = (const bs8*)(GF + ((size_t)((b << 15) + n)) * 128 + seg * 32);
  bs8 g0 = gp[0], g1 = gp[1], g2 = gp[2], g3 = gp[3];
  if (seg == 0) {  // exact mask (fp32 arith, double cmp — replicates setup bit-exactly)
    float la = latg[(q0 + qh) * 3], lb = latg[(q0 + qh) * 3 + 1], lc = latg[(q0 + qh) * 3 + 2];
    float d0 = __fsub_rn(la, gc[n * 3]);
    float d1 = __fsub_rn(lb, gc[n * 3 + 1]);
    float d2 = __fsub_rn(lc, gc[n * 3 + 2]);
    float s = __fadd_rn(__fadd_rn(__fmul_rn(d0, d0), __fmul_rn(d1, d1)), __fmul_rn(d2, d2));
    maskfS[r] = ((double)s <= 0.055 * 0.055) ? 1.0f : 0.0f;
  }
  __syncthreads();  // vqS ready (maskf consumed after later barriers)
  {  // h0 = gelu(GF + vq)
    const float* vrow = vqS[qh] + seg * 32;
    *(uint4*)(&h0S[r][seg * 32]) = gelu8(g0, vrow);
    *(uint4*)(&h0S[r][seg * 32 + 8]) = gelu8(g1, vrow + 8);
    *(uint4*)(&h0S[r][seg * 32 + 16]) = gelu8(g2, vrow + 16);
    *(uint4*)(&h0S[r][seg * 32 + 24]) = gelu8(g3, vrow + 24);
  }
  __syncthreads();  // h0S + mask ready
  if (tid < 2) {
    float s = 0.0f;
#pragma unroll
    for (int i = 0; i < 32; ++i) s += maskfS[tid * 32 + i];
    cntG[(b << 12) + q0 + tid] = s;
  }

  const int wid = tid >> 6, lane = tid & 63;
  const int l15 = lane & 15, lg = lane >> 4;
  const int mh = wid >> 1, nh = wid & 1;  // L2 roles
  f4 accL2[4][2] = {};                    // persists across chunks

#pragma unroll 1
  for (int c = 0; c < 2; ++c) {
    {  // L1 chunk: wave owns 32 feats (local f0l..f0l+31) x all 64 rows
      const int f0l = wid * 32;
      const int fg = c * 128 + f0l;  // global h1 feature base
      f4 acc[2][4] = {};
#pragma unroll
      for (int ks = 0; ks < 4; ++ks) {
        bs8 Aw[2], Bh[4];
#pragma unroll
        for (int ft = 0; ft < 2; ++ft)
          Aw[ft] = *(const bs8*)(W1T + (fg + ft * 16 + l15) * 128 + ks * 32 + lg * 8);
#pragma unroll
        for (int rt = 0; rt < 4; ++rt)
          Bh[rt] = *(const bs8*)(&h0S[rt * 16 + l15][ks * 32 + lg * 8]);
#pragma unroll
        for (int ft = 0; ft < 2; ++ft)
#pragma unroll
          for (int rt = 0; rt < 4; ++rt)
            acc[ft][rt] = MFMA16(Aw[ft], Bh[rt], acc[ft][rt], 0, 0, 0);
      }
#pragma unroll
      for (int ft = 0; ft < 2; ++ft) {
        f4 bias = *(const f4*)(b1 + fg + ft * 16 + lg * 4);
#pragma unroll
        for (int rt = 0; rt < 4; ++rt) {
          float v0 = gelu_t(acc[ft][rt][0] + bias[0]);
          float v1 = gelu_t(acc[ft][rt][1] + bias[1]);
          float v2 = gelu_t(acc[ft][rt][2] + bias[2]);
          float v3 = gelu_t(acc[ft][rt][3] + bias[3]);
          uint2 p;
          p.x = pk2bf(v0, v1);
          p.y = pk2bf(v2, v3);
          *(uint2*)(&h1S[rt * 16 + l15][f0l + ft * 16 + lg * 4]) = p;
        }
      }
    }
    __syncthreads();  // h1 chunk ready
    {  // L2 partial-K accumulate: wave (mh: 32 rows) x (nh: 64 out-feats)
      const int fo = nh * 64;
#pragma unroll
      for (int ks = 0; ks < 4; ++ks) {
        bs8 Ah[2], Bw[4];
#pragma unroll
        for (int rt = 0; rt < 2; ++rt)
          Ah[rt] = *(const bs8*)(&h1S[mh * 32 + rt * 16 + l15][ks * 32 + lg * 8]);
#pragma unroll
        for (int ct = 0; ct < 4; ++ct)
          Bw[ct] = *(const bs8*)(W2T + (fo + ct * 16 + l15) * 256 + c * 128 + ks * 32 + lg * 8);
#pragma unroll
        for (int ct = 0; ct < 4; ++ct)
#pragma unroll
          for (int rt = 0; rt < 2; ++rt)
            accL2[ct][rt] = MFMA16(Ah[rt], Bw[ct], accL2[ct][rt], 0, 0, 0);
      }
    }
    __syncthreads();  // done reading h1 chunk before overwrite
  }

  {  // L2 epilogue: gelu + mask + per-q row-sum -> staged
    const int fo = nh * 64;
    float psum[4];
#pragma unroll
    for (int ct = 0; ct < 4; ++ct) {
      float bias = b2[fo + ct * 16 + l15];
      float s = 0.0f;
#pragma unroll
      for (int rt = 0; rt < 2; ++rt)
#pragma unroll
        for (int i = 0; i < 4; ++i) {
          int row = mh * 32 + rt * 16 + lg * 4 + i;
          s += gelu_t(accL2[ct][rt][i] + bias) * maskfS[row];
        }
      psum[ct] = s;
    }
#pragma unroll
    for (int ct = 0; ct < 4; ++ct) {
      psum[ct] += __shfl_xor(psum[ct], 16, 64);
      psum[ct] += __shfl_xor(psum[ct], 32, 64);
    }
    if (lane < 16) {
      float* op = staged + ((size_t)((b << 12) + q0 + mh)) * 128 + fo;
      op[lane] = psum[0];
      op[16 + lane] = psum[1];
      op[32 + lane] = psum[2];
      op[48 + lane] = psum[3];
    }
  }
}

// fin2: out = h2sum @ W3 + cnt*b3 with transpose. Block = 256 q (one hi), 4 waves.
__global__ __launch_bounds__(256, 2) void gno_fin2(
    const float* __restrict__ staged, const float* __restrict__ cntG,
    const short* __restrict__ W3T, const float* __restrict__ b3,
    float* __restrict__ out) {
  __shared__ __align__(16) float tileS[16 * 260];  // [16 feats][256 rows pad 260]
  __shared__ float cntS[256];
  __shared__ float b3S[128];
  const int tid = threadIdx.x, blk = blockIdx.x;
  const int b = blk >> 4;
  const int q0 = (blk & 15) * 256;
  const int hi = blk & 15;
  cntS[tid] = cntG[(b << 12) + q0 + tid];
  if (tid < 128) b3S[tid] = b3[tid];
  __syncthreads();
  const int wid = tid >> 6, lane = tid & 63;
  const int l15 = lane & 15, lg = lane >> 4;
  const int r0 = wid * 64;  // wave's 64 rows
  f4 acc[8][4] = {};        // [ct(feat)][rt(row)]; C: col=q(l15), row=feat(lg*4+i)
#pragma unroll
  for (int ks = 0; ks < 4; ++ks) {
    bs8 Aa[4];
#pragma unroll
    for (int rt = 0; rt < 4; ++rt) {
      const float* ap =
          staged + ((size_t)(b << 12) + q0 + r0 + rt * 16 + l15) * 128 + ks * 32 + lg * 8;
      f4 a0 = *(const f4*)ap;
      f4 a1 = *(const f4*)(ap + 4);
      uint4 uu;
      uu.x = pk2bf(a0[0], a0[1]);
      uu.y = pk2bf(a0[2], a0[3]);
      uu.z = pk2bf(a1[0], a1[1]);
      uu.w = pk2bf(a1[2], a1[3]);
      Aa[rt] = *reinterpret_cast<bs8*>(&uu);
    }
#pragma unroll
    for (int ct = 0; ct < 8; ++ct) {
      bs8 Bw = *(const bs8*)(W3T + (ct * 16 + l15) * 128 + ks * 32 + lg * 8);
#pragma unroll
      for (int rt = 0; rt < 4; ++rt)
        acc[ct][rt] = MFMA16(Bw, Aa[rt], acc[ct][rt], 0, 0, 0);
    }
  }
#pragma unroll 1
  for (int ct = 0; ct < 8; ++ct) {
#pragma unroll
    for (int rt = 0; rt < 4; ++rt) {
      int rr = r0 + rt * 16 + l15;
      float cv = cntS[rr];
#pragma unroll
      for (int i = 0; i < 4; ++i) {
        int fl = lg * 4 + i;
        tileS[fl * 260 + rr] = acc[ct][rt][i] + cv * b3S[ct * 16 + fl];
      }
    }
    __syncthreads();
    {  // coalesced out: thread owns (feat fl, dl); 16 consecutive wj floats
      int fl = tid >> 4, dl = tid & 15;
      int o = ct * 16 + fl;
      float* dst = out + ((size_t)b << 19) + (o << 12) + (dl << 8) + (hi << 4);
#pragma unroll
      for (int w4 = 0; w4 < 4; ++w4) {
        float4 t;
        t.x = tileS[fl * 260 + (w4 * 4 + 0) * 16 + dl];
        t.y = tileS[fl * 260 + (w4 * 4 + 1) * 16 + dl];
        t.z = tileS[fl * 260 + (w4 * 4 + 2) * 16 + dl];
        t.w = tileS[fl * 260 + (w4 * 4 + 3) * 16 + dl];
        *(float4*)(dst + w4 * 4) = t;
      }
    }
    __syncthreads();
  }
}

// =================== old (fallback) path — round-1 kernels ===================

__global__ void gno_prep(const float* __restrict__ W0, const float* __restrict__ W1,
                         const float* __restrict__ W2, const float* __restrict__ W3,
                         short* __restrict__ W0aT, short* __restrict__ W1T,
                         short* __restrict__ W2T, short* __restrict__ W3T) {
  int g = blockIdx.x * 256 + threadIdx.x;
  if (g < 16384) {
    int n = g >> 7, k = g & 127;
    float v = (k < 96) ? W0[k * 128 + n] : ((k < 100) ? W0[(k + 96) * 128 + n] : 0.0f);
    W0aT[g] = f2bf(v);
  } else if (g < 49152) {
    int h = g - 16384, n = h >> 7, k = h & 127;
    W1T[h] = f2bf(W1[k * 256 + n]);
  } else if (g < 81920) {
    int h = g - 49152, n = h >> 8, k = h & 255;
    W2T[h] = f2bf(W2[k * 128 + n]);
  } else if (g < 98304) {
    int h = g - 81920, n = h >> 7, k = h & 127;
    W3T[h] = f2bf(W3[k * 128 + n]);
  }
}

template <int SIN, int K>
__device__ __forceinline__ void gemm_block(const short* inS, const short* __restrict__ WT,
                                           int colBase, int lane, f4 (&acc)[2][4]) {
  constexpr int KS = K / 32;
  bs8 Bf[2][KS];
  const int bcol = lane & 15;
  const int bk = (lane >> 4) * 8;
#pragma unroll
  for (int ct = 0; ct < 2; ++ct)
#pragma unroll
    for (int ks = 0; ks < KS; ++ks)
      Bf[ct][ks] = *reinterpret_cast<const bs8*>(WT + (colBase + ct * 16 + bcol) * K + ks * 32 + bk);
#pragma unroll
  for (int mt = 0; mt < 4; ++mt) {
#pragma unroll
    for (int ks = 0; ks < KS; ++ks) {
      bs8 Af = *reinterpret_cast<const bs8*>(inS + (mt * 16 + bcol) * SIN + ks * 32 + bk);
      acc[0][mt] = MFMA16(Af, Bf[0][ks], acc[0][mt], 0, 0, 0);
      acc[1][mt] = MFMA16(Af, Bf[1][ks], acc[1][mt], 0, 0, 0);
    }
  }
}

__global__ __launch_bounds__(256, 2) void gno_main(
    const float* __restrict__ x, const float* __restrict__ gc,
    const float* __restrict__ latg, const int* __restrict__ nidx,
    const float* __restrict__ W0, const float* __restrict__ b0,
    const float* __restrict__ b1, const float* __restrict__ b2,
    const float* __restrict__ b3,
    const short* __restrict__ W0aT, const short* __restrict__ W1T,
    const short* __restrict__ W2T, const short* __restrict__ W3T,
    float* __restrict__ dst, int direct) {
  __shared__ __align__(16) short aggS[64][136];
  __shared__ __align__(16) short h0S[64][136];
  __shared__ __align__(16) short h1S[64][264];
  __shared__ float vqS[2][128];
  __shared__ float maskfS[64];
  __shared__ float freqS[16];
  __shared__ float latS[2][3];
  __shared__ float sEmbQ[2][96];

  const int tid = threadIdx.x;
  const int blk = blockIdx.x;
  const int b = blk >> 11;
  const int q0 = (blk & 2047) * 2;

  if (tid < 16) freqS[tid] = (float)exp(-(double)tid * (9.210340371976184 / 16.0));
  if (tid >= 32 && tid < 38) {
    int t = tid - 32, qh = t / 3, a = t % 3;
    latS[qh][a] = latg[(q0 + qh) * 3 + a];
  }
  __syncthreads();
  if (tid < 192) {
    int qh = tid / 96, c = tid % 96, a = c >> 5, jj = c & 31;
    float ca = latS[qh][a];
    sEmbQ[qh][c] = (jj < 16) ? __sinf(ca * freqS[jj]) : __cosf(ca * freqS[jj & 15]);
  }
  __syncthreads();
  {
    int qh = tid >> 7, o = tid & 127;
    float s = b0[o];
#pragma unroll 4
    for (int j = 0; j < 96; ++j) s = fmaf(sEmbQ[qh][j], W0[(96 + j) * 128 + o], s);
    vqS[qh][o] = s;
  }
  {
    int r = tid >> 2, qq = tid & 3;
    int qh = r >> 5, kk = r & 31;
    int n = nidx[(q0 + qh) * 32 + kk];
    float c0 = gc[n * 3], c1 = gc[n * 3 + 1], c2 = gc[n * 3 + 2];
    if (qq == 0) {
      float d0 = __fsub_rn(latS[qh][0], c0);
      float d1 = __fsub_rn(latS[qh][1], c1);
      float d2 = __fsub_rn(latS[qh][2], c2);
      float s = __fadd_rn(__fadd_rn(__fmul_rn(d0, d0), __fmul_rn(d1, d1)), __fmul_rn(d2, d2));
      maskfS[r] = ((double)s <= 0.055 * 0.055) ? 1.0f : 0.0f;
    }
    float cc[3] = {c0, c1, c2};
    for (int c = qq * 34; c < qq * 34 + 34; ++c) {
      float v = 0.0f;
      if (c < 96) {
        int a = c >> 5, jj = c & 31;
        v = (jj < 16) ? __sinf(cc[a] * freqS[jj]) : __cosf(cc[a] * freqS[jj & 15]);
      } else if (c < 100) {
        int ch = c - 96;
        v = x[((b * 4 + ch) << 15) + ((n & 31) << 10) + (n >> 5)];
      }
      aggS[r][c] = f2bf(v);
    }
  }
  __syncthreads();

  const int wave = tid >> 6, lane = tid & 63;
  const int colBase = wave * 32;
  const int lrow4 = (lane >> 4) << 2;
  const int lcol = lane & 15;

  {
    f4 acc[2][4] = {};
    gemm_block<136, 128>(&aggS[0][0], W0aT, colBase, lane, acc);
#pragma unroll
    for (int ct = 0; ct < 2; ++ct) {
      int gcol = colBase + ct * 16 + lcol;
#pragma unroll
      for (int mt = 0; mt < 4; ++mt)
#pragma unroll
        for (int i = 0; i < 4; ++i) {
          int grow = mt * 16 + lrow4 + i;
          h0S[grow][gcol] = f2bf(gelu_old(acc[ct][mt][i] + vqS[grow >> 5][gcol]));
        }
    }
  }
  __syncthreads();
  {
#pragma unroll 1
    for (int cg = 0; cg < 2; ++cg) {
      int cb = wave * 64 + cg * 32;
      f4 acc[2][4] = {};
      gemm_block<136, 128>(&h0S[0][0], W1T, cb, lane, acc);
#pragma unroll
      for (int ct = 0; ct < 2; ++ct) {
        int gcol = cb + ct * 16 + lcol;
        float bias = b1[gcol];
#pragma unroll
        for (int mt = 0; mt < 4; ++mt)
#pragma unroll
          for (int i = 0; i < 4; ++i) {
            int grow = mt * 16 + lrow4 + i;
            h1S[grow][gcol] = f2bf(gelu_old(acc[ct][mt][i] + bias));
          }
      }
    }
  }
  __syncthreads();
  {
    f4 acc[2][4] = {};
    gemm_block<264, 256>(&h1S[0][0], W2T, colBase, lane, acc);
#pragma unroll
    for (int ct = 0; ct < 2; ++ct) {
      int gcol = colBase + ct * 16 + lcol;
      float bias = b2[gcol];
#pragma unroll
      for (int mt = 0; mt < 4; ++mt)
#pragma unroll
        for (int i = 0; i < 4; ++i) {
          int grow = mt * 16 + lrow4 + i;
          aggS[grow][gcol] = f2bf(gelu_old(acc[ct][mt][i] + bias));
        }
    }
  }
  __syncthreads();
  {
    f4 acc[2][4] = {};
    gemm_block<136, 128>(&aggS[0][0], W3T, colBase, lane, acc);
    float part[2][2] = {{0.0f, 0.0f}, {0.0f, 0.0f}};
#pragma unroll
    for (int ct = 0; ct < 2; ++ct) {
      float bias = b3[colBase + ct * 16 + lcol];
#pragma unroll
      for (int mt = 0; mt < 4; ++mt)
#pragma unroll
        for (int i = 0; i < 4; ++i) {
          int grow = mt * 16 + lrow4 + i;
          part[mt >> 1][ct] += (acc[ct][mt][i] + bias) * maskfS[grow];
        }
    }
#pragma unroll
    for (int qh = 0; qh < 2; ++qh)
#pragma unroll
      for (int ct = 0; ct < 2; ++ct) {
        float v = part[qh][ct];
        v += __shfl_xor(v, 16, 64);
        v += __shfl_xor(v, 32, 64);
        if (lane < 16) {
          int o = colBase + ct * 16 + lane;
          int q = q0 + qh;
          if (direct)
            dst[(b << 19) + (o << 12) + ((q & 15) << 8) + ((q >> 8) << 4) + ((q >> 4) & 15)] = v;
          else
            dst[(b * 4096 + q) * 128 + o] = v;
        }
      }
  }
}

__global__ void gno_tr(const float* __restrict__ staged, float* __restrict__ out) {
  __shared__ float tile[16][129];
  int blk = blockIdx.x;
  int b = blk >> 8, i = (blk >> 4) & 15, l = blk & 15;
  int t = threadIdx.x;
  {
    int j = t >> 4, oc = t & 15;
    const float* src = staged + ((b * 4096) + (i * 256 + j * 16 + l)) * 128 + oc * 8;
#pragma unroll
    for (int u = 0; u < 8; ++u) tile[j][oc * 8 + u] = src[u];
  }
  __syncthreads();
  {
    int og = t >> 4, j = t & 15;
#pragma unroll
    for (int oo = 0; oo < 8; ++oo) {
      int o = og * 8 + oo;
      out[(b << 19) + (o << 12) + (l << 8) + (i << 4) + j] = tile[j][o];
    }
  }
}

extern "C" void kernel_launch(void* const* d_in, const int* in_sizes, int n_in,
                              void* d_out, int out_size, void* d_ws, size_t ws_size,
                              hipStream_t stream) {
  const float* x    = (const float*)d_in[0];
  const float* gc   = (const float*)d_in[1];
  const float* latg = (const float*)d_in[2];
  const int*   nidx = (const int*)d_in[3];
  const float* W0 = (const float*)d_in[5];
  const float* b0 = (const float*)d_in[6];
  const float* W1 = (const float*)d_in[7];
  const float* b1 = (const float*)d_in[8];
  const float* W2 = (const float*)d_in[9];
  const float* b2 = (const float*)d_in[10];
  const float* W3 = (const float*)d_in[11];
  const float* b3 = (const float*)d_in[12];

  char* ws = (char*)d_ws;
  float* out = (float*)d_out;

  if (ws_size >= (size_t)FAST_NEED) {
    short* W1T = (short*)(ws + W1T_OFF);
    short* W2T = (short*)(ws + W2T_OFF);
    short* W3T = (short*)(ws + W3T_OFF);
    float* vqPre = (float*)(ws + VQ_OFF);
    short* GF = (short*)(ws + GF_OFF);
    float* staged = (float*)(ws + ST_OFF);
    float* cntG = (float*)(ws + CNT_OFF);
    gno_pre<<<2880, 256, 0, stream>>>(x, gc, latg, W0, b0, W1, W2, W3,
                                      W1T, W2T, W3T, vqPre, GF);
    gno_main4<<<4096, 256, 0, stream>>>(gc, latg, nidx, b1, b2,
                                        W1T, W2T, vqPre, GF, staged, cntG);
    gno_fin2<<<32, 256, 0, stream>>>(staged, cntG, W3T, b3, out);
  } else {
    short* W0aT = (short*)(ws + OW0AT_OFF);
    short* W1T  = (short*)(ws + OW1T_OFF);
    short* W2T  = (short*)(ws + OW2T_OFF);
    short* W3T  = (short*)(ws + OW3T_OFF);
    float* staged = (float*)(ws + OSTAGED_OFF);
    const bool use_staged = (ws_size >= (size_t)OLD_NEED);
    gno_prep<<<384, 256, 0, stream>>>(W0, W1, W2, W3, W0aT, W1T, W2T, W3T);
    gno_main<<<4096, 256, 0, stream>>>(x, gc, latg, nidx, W0, b0, b1, b2, b3,
                                       W0aT, W1T, W2T, W3T,
                                       use_staged ? staged : out, use_staged ? 0 : 1);
    if (use_staged) gno_tr<<<512, 256, 0, stream>>>(staged, out);
  }
}

// Round 6
// 241.759 us; speedup vs baseline: 1.1768x; 1.1768x over previous
//
#include <hip/hip_runtime.h>
#include <hip/hip_bf16.h>
#include <math.h>

// GNO stem, round 6.
//  - main is VALU-bound on gelu (134M gelus x 18cy = 61us ~ measured 66us VALU).
//    Fix: packed-f32 gelu (v_pk_fma_f32) on float2 -> 5 pk inst/2 elems, same math.
//  - aux regression (R5 merged pre = 151us): un-merge; vq now MFMA-based (64 blocks)
//    inside the GF kernel; weight transposes in tiny prep3; fin2 split to 64 blocks.
//  - 4 launches: prep3 -> gfvq -> main5 -> fin2.

typedef short bs8 __attribute__((ext_vector_type(8)));
typedef float f4  __attribute__((ext_vector_type(4)));
typedef float f2  __attribute__((ext_vector_type(2)));

#define MFMA16 __builtin_amdgcn_mfma_f32_16x16x32_bf16

// ---------- fast-path ws layout (bytes) ----------
#define W1T_OFF    0u          // [256][128] bf16  65536
#define W2T_OFF    65536u      // [128][256] bf16  65536
#define W3T_OFF    131072u     // [128][128] bf16  32768
#define W0ET_OFF   163840u     // [128][96]  bf16  24576
#define W0MT_OFF   188416u     // [128][96]  bf16  24576
#define VQ_OFF     212992u     // [4096][128] f32  2097152
#define GF_OFF     2310144u    // [2][32768][128] bf16 16777216
#define ST_OFF     19087360u   // [2][4096][128] f32 4194304
#define CNT_OFF    23281664u   // [8192] f32 32768
#define FAST_NEED  23314432u

// ---------- old-path ws layout ----------
#define OW0AT_OFF   0
#define OW1T_OFF    32768
#define OW2T_OFF    98304
#define OW3T_OFF    163840
#define OSTAGED_OFF 196608
#define OLD_NEED    (196608 + 4194304)

__device__ __forceinline__ short f2bf(float f) {
  unsigned u = __float_as_uint(f);
  return (short)((u + 0x7FFFu + ((u >> 16) & 1u)) >> 16);  // RNE
}
__device__ __forceinline__ float bf2f(short s) {
  return __uint_as_float(((unsigned)(unsigned short)s) << 16);
}
__device__ __forceinline__ unsigned pk2bf(float lo, float hi) {
  __hip_bfloat162 h = __float22bfloat162_rn(float2{lo, hi});  // v_cvt_pk_bf16_f32
  return *reinterpret_cast<unsigned*>(&h);
}
// packed gelu: x*E/(1+E), E = 2^(x*(a + a*0.044715*x^2)). 5 pk-VALU + 2x{exp2,rcp}.
__device__ __forceinline__ f2 gelu2(f2 x) {
  f2 t = x * x;
  f2 z = x * (t * 0.10294322f + 2.3022077f);
  f2 e;
  e.x = __builtin_exp2f(z.x);
  e.y = __builtin_exp2f(z.y);
  f2 d = e + 1.0f;
  f2 r;
  r.x = __builtin_amdgcn_rcpf(d.x);
  r.y = __builtin_amdgcn_rcpf(d.y);
  return x - x * r;
}
__device__ __forceinline__ float gelu_old(float x) {
  float z = 0.7978845608028654f * fmaf(0.044715f * x, x * x, x);
  float e = __expf(2.0f * z);
  return 0.5f * x * (2.0f - 2.0f / (e + 1.0f));
}

// =================== fast path ===================

// prep3: all weight transposes. 106496 elems, 416 blocks.
__global__ void gno_prep3(const float* __restrict__ W0, const float* __restrict__ W1,
                          const float* __restrict__ W2, const float* __restrict__ W3,
                          short* __restrict__ W1T, short* __restrict__ W2T,
                          short* __restrict__ W3T, short* __restrict__ W0eT,
                          short* __restrict__ W0mT) {
  int g = blockIdx.x * 256 + threadIdx.x;
  if (g < 32768) {                 // W1T [256][128]
    int nn = g >> 7, k = g & 127;
    W1T[g] = f2bf(W1[k * 256 + nn]);
  } else if (g < 65536) {          // W2T [128][256]
    int h = g - 32768, nn = h >> 8, k = h & 255;
    W2T[h] = f2bf(W2[k * 128 + nn]);
  } else if (g < 81920) {          // W3T [128][128]
    int h = g - 65536, nn = h >> 7, k = h & 127;
    W3T[h] = f2bf(W3[k * 128 + nn]);
  } else if (g < 94208) {          // W0eT [128][96]
    int h = g - 81920, nn = h / 96, k = h % 96;
    W0eT[h] = f2bf(W0[k * 128 + nn]);
  } else if (g < 106496) {         // W0mT [128][96]
    int h = g - 94208, nn = h / 96, k = h % 96;
    W0mT[h] = f2bf(W0[(96 + k) * 128 + nn]);
  }
}

// gfvq: blocks [0,512) GF (64 input points each); [512,576) vq (64 latent pts each).
__global__ __launch_bounds__(256, 4) void gno_gfvq(
    const float* __restrict__ x, const float* __restrict__ gc,
    const float* __restrict__ latg, const float* __restrict__ W0,
    const float* __restrict__ b0,
    const short* __restrict__ W0eT, const short* __restrict__ W0mT,
    short* __restrict__ GF, float* __restrict__ vqPre) {
  __shared__ __align__(16) short embS[64 * 104];   // 13312
  __shared__ __align__(16) short tileS[64 * 132];  // 16896 (GF only)
  __shared__ float gcS[192];                       // coords (gc or lat)
  __shared__ float xS[2][4][64];                   // GF only
  __shared__ float wfS[4][128];                    // GF only
  __shared__ float freqS[16];

  const int tid = threadIdx.x;
  const int blk = blockIdx.x;
  const bool isGF = blk < 512;
  const int p0 = isGF ? blk * 64 : (blk - 512) * 64;  // point / latent base

  if (tid < 16) freqS[tid] = (float)exp(-(double)tid * (9.210340371976184 / 16.0));
  if (tid < 192) gcS[tid] = isGF ? gc[p0 * 3 + tid] : latg[p0 * 3 + tid];
  if (isGF) {
#pragma unroll
    for (int u = 0; u < 2; ++u) {
      int slot = tid * 2 + u;  // 512 slots
      int bb = slot >> 8, ch = (slot >> 6) & 3, i = slot & 63;
      int n = p0 + i;
      xS[bb][ch][i] = x[((bb * 4 + ch) << 15) + ((n & 31) << 10) + (n >> 5)];
      wfS[slot >> 7][slot & 127] = W0[(192 + (slot >> 7)) * 128 + (slot & 127)];
    }
  }
  __syncthreads();
  {  // embedding trig: 64 rows x 96 cols
    int rr = tid >> 2, c4 = tid & 3;
#pragma unroll
    for (int c = c4 * 24; c < c4 * 24 + 24; ++c) {
      int a = c >> 5, jj = c & 31;
      float v = (jj < 16) ? __sinf(gcS[rr * 3 + a] * freqS[jj])
                          : __cosf(gcS[rr * 3 + a] * freqS[jj & 15]);
      embS[rr * 104 + c] = f2bf(v);
    }
  }
  __syncthreads();
  const int wid = tid >> 6, lane = tid & 63;
  const int l15 = lane & 15, lg = lane >> 4;
  const int f0 = wid * 32;
  const short* WT = isGF ? W0eT : W0mT;
  f4 acc[2][4] = {};  // [ftile][ptile]; C: col=point(l15), row=feat(lg*4+i)
#pragma unroll
  for (int ks = 0; ks < 3; ++ks) {
    bs8 Aw[2], Be[4];
#pragma unroll
    for (int ft = 0; ft < 2; ++ft)
      Aw[ft] = *(const bs8*)(WT + (f0 + ft * 16 + l15) * 96 + ks * 32 + lg * 8);
#pragma unroll
    for (int pt = 0; pt < 4; ++pt)
      Be[pt] = *(const bs8*)(embS + (pt * 16 + l15) * 104 + ks * 32 + lg * 8);
#pragma unroll
    for (int ft = 0; ft < 2; ++ft)
#pragma unroll
      for (int pt = 0; pt < 4; ++pt)
        acc[ft][pt] = MFMA16(Aw[ft], Be[pt], acc[ft][pt], 0, 0, 0);
  }
  if (!isGF) {  // vq epilogue: vqPre[q][f] = acc + b0[f], f32
#pragma unroll
    for (int ft = 0; ft < 2; ++ft) {
      f4 bias = *(const f4*)(b0 + f0 + ft * 16 + lg * 4);
#pragma unroll
      for (int pt = 0; pt < 4; ++pt) {
        int q = p0 + pt * 16 + l15;
        *(f4*)(vqPre + q * 128 + f0 + ft * 16 + lg * 4) = acc[ft][pt] + bias;
      }
    }
    return;
  }
  // GF epilogue: + x@W0[192:196], pack bf16, LDS transpose, coalesced store
#pragma unroll 1
  for (int bb = 0; bb < 2; ++bb) {
#pragma unroll
    for (int ft = 0; ft < 2; ++ft) {
      f4 wf0 = *(const f4*)(&wfS[0][f0 + ft * 16 + lg * 4]);
      f4 wf1 = *(const f4*)(&wfS[1][f0 + ft * 16 + lg * 4]);
      f4 wf2 = *(const f4*)(&wfS[2][f0 + ft * 16 + lg * 4]);
      f4 wf3 = *(const f4*)(&wfS[3][f0 + ft * 16 + lg * 4]);
#pragma unroll
      for (int pt = 0; pt < 4; ++pt) {
        int p = pt * 16 + l15;
        float x0 = xS[bb][0][p], x1 = xS[bb][1][p], x2 = xS[bb][2][p], x3 = xS[bb][3][p];
        float v0 = acc[ft][pt][0] + x0 * wf0[0] + x1 * wf1[0] + x2 * wf2[0] + x3 * wf3[0];
        float v1 = acc[ft][pt][1] + x0 * wf0[1] + x1 * wf1[1] + x2 * wf2[1] + x3 * wf3[1];
        float v2 = acc[ft][pt][2] + x0 * wf0[2] + x1 * wf1[2] + x2 * wf2[2] + x3 * wf3[2];
        float v3 = acc[ft][pt][3] + x0 * wf0[3] + x1 * wf1[3] + x2 * wf2[3] + x3 * wf3[3];
        uint2 pp;
        pp.x = pk2bf(v0, v1);
        pp.y = pk2bf(v2, v3);
        *(uint2*)(tileS + p * 132 + f0 + ft * 16 + lg * 4) = pp;
      }
    }
    __syncthreads();
    {  // coalesced copy-out: 64 rows x 256B
      int row = tid >> 2, c4 = tid & 3;
      const short* src = tileS + row * 132 + c4 * 32;
      short* dst = GF + ((size_t)((bb << 15) + p0 + row)) * 128 + c4 * 32;
      *(uint4*)(dst)      = *(const uint4*)(src);
      *(uint4*)(dst + 8)  = *(const uint4*)(src + 8);
      *(uint4*)(dst + 16) = *(const uint4*)(src + 16);
      *(uint4*)(dst + 24) = *(const uint4*)(src + 24);
    }
    __syncthreads();
  }
}

// h0: gelu(GF + vq) for 8 bf16 packed in a uint4, fully pk.
__device__ __forceinline__ uint4 gelu8u(uint4 gu, const float* vrow) {
  uint4 r;
  const unsigned ua[4] = {gu.x, gu.y, gu.z, gu.w};
  unsigned ro[4];
#pragma unroll
  for (int j = 0; j < 4; ++j) {
    f2 xx;
    xx.x = __uint_as_float(ua[j] << 16);
    xx.y = __uint_as_float(ua[j] & 0xFFFF0000u);
    xx += *(const f2*)(vrow + 2 * j);
    f2 g = gelu2(xx);
    ro[j] = pk2bf(g.x, g.y);
  }
  r.x = ro[0]; r.y = ro[1]; r.z = ro[2]; r.w = ro[3];
  return r;
}

// main5: block = (b, 2 q) = 64 rows; 4 waves; h1 in 2x128-col chunks; pk gelu.
__global__ __launch_bounds__(256, 4) void gno_main5(
    const float* __restrict__ gc, const float* __restrict__ latg,
    const int* __restrict__ nidx,
    const float* __restrict__ b1, const float* __restrict__ b2,
    const short* __restrict__ W1T, const short* __restrict__ W2T,
    const float* __restrict__ vqPre, const short* __restrict__ GF,
    float* __restrict__ staged, float* __restrict__ cntG) {
  __shared__ __align__(16) short h0S[64][136];
  __shared__ __align__(16) short h1S[64][136];
  __shared__ float vqS[2][128];
  __shared__ float maskfS[64];

  const int tid = threadIdx.x;
  const int blk = blockIdx.x;
  const int b = blk >> 11;
  const int q0 = (blk & 2047) * 2;

  vqS[tid >> 7][tid & 127] = vqPre[(q0 + (tid >> 7)) * 128 + (tid & 127)];

  const int r = tid >> 2, seg = tid & 3;
  const int qh = r >> 5;
  const int n = nidx[(q0 + qh) * 32 + (r & 31)];
  const uint4* gp = (const uint4*)(GF + ((size_t)((b << 15) + n)) * 128 + seg * 32);
  uint4 g0 = gp[0], g1 = gp[1], g2 = gp[2], g3 = gp[3];
  if (seg == 0) {  // exact mask (fp32 arith, double cmp — replicates setup bit-exactly)
    float la = latg[(q0 + qh) * 3], lb = latg[(q0 + qh) * 3 + 1], lc = latg[(q0 + qh) * 3 + 2];
    float d0 = __fsub_rn(la, gc[n * 3]);
    float d1 = __fsub_rn(lb, gc[n * 3 + 1]);
    float d2 = __fsub_rn(lc, gc[n * 3 + 2]);
    float s = __fadd_rn(__fadd_rn(__fmul_rn(d0, d0), __fmul_rn(d1, d1)), __fmul_rn(d2, d2));
    maskfS[r] = ((double)s <= 0.055 * 0.055) ? 1.0f : 0.0f;
  }
  __syncthreads();  // vqS ready
  {  // h0 = gelu(GF + vq)
    const float* vrow = vqS[qh] + seg * 32;
    *(uint4*)(&h0S[r][seg * 32]) = gelu8u(g0, vrow);
    *(uint4*)(&h0S[r][seg * 32 + 8]) = gelu8u(g1, vrow + 8);
    *(uint4*)(&h0S[r][seg * 32 + 16]) = gelu8u(g2, vrow + 16);
    *(uint4*)(&h0S[r][seg * 32 + 24]) = gelu8u(g3, vrow + 24);
  }
  __syncthreads();  // h0S + mask ready
  if (tid < 2) {
    float s = 0.0f;
#pragma unroll
    for (int i = 0; i < 32; ++i) s += maskfS[tid * 32 + i];
    cntG[(b << 12) + q0 + tid] = s;
  }

  const int wid = tid >> 6, lane = tid & 63;
  const int l15 = lane & 15, lg = lane >> 4;
  const int mh = wid >> 1, nh = wid & 1;  // L2 roles
  f4 accL2[4][2] = {};                    // persists across chunks

#pragma unroll 1
  for (int c = 0; c < 2; ++c) {
    {  // L1 chunk: wave owns 32 feats x all 64 rows
      const int f0l = wid * 32;
      const int fg = c * 128 + f0l;
      f4 acc[2][4] = {};
#pragma unroll
      for (int ks = 0; ks < 4; ++ks) {
        bs8 Aw[2], Bh[4];
#pragma unroll
        for (int ft = 0; ft < 2; ++ft)
          Aw[ft] = *(const bs8*)(W1T + (fg + ft * 16 + l15) * 128 + ks * 32 + lg * 8);
#pragma unroll
        for (int rt = 0; rt < 4; ++rt)
          Bh[rt] = *(const bs8*)(&h0S[rt * 16 + l15][ks * 32 + lg * 8]);
#pragma unroll
        for (int ft = 0; ft < 2; ++ft)
#pragma unroll
          for (int rt = 0; rt < 4; ++rt)
            acc[ft][rt] = MFMA16(Aw[ft], Bh[rt], acc[ft][rt], 0, 0, 0);
      }
#pragma unroll
      for (int ft = 0; ft < 2; ++ft) {
        f4 bias = *(const f4*)(b1 + fg + ft * 16 + lg * 4);
#pragma unroll
        for (int rt = 0; rt < 4; ++rt) {
          f2 a = {acc[ft][rt][0] + bias[0], acc[ft][rt][1] + bias[1]};
          f2 bpair = {acc[ft][rt][2] + bias[2], acc[ft][rt][3] + bias[3]};
          f2 ga = gelu2(a);
          f2 gb = gelu2(bpair);
          uint2 p;
          p.x = pk2bf(ga.x, ga.y);
          p.y = pk2bf(gb.x, gb.y);
          *(uint2*)(&h1S[rt * 16 + l15][f0l + ft * 16 + lg * 4]) = p;
        }
      }
    }
    __syncthreads();  // h1 chunk ready
    {  // L2 partial-K accumulate: wave (mh: 32 rows) x (nh: 64 out-feats)
      const int fo = nh * 64;
#pragma unroll
      for (int ks = 0; ks < 4; ++ks) {
        bs8 Ah[2], Bw[4];
#pragma unroll
        for (int rt = 0; rt < 2; ++rt)
          Ah[rt] = *(const bs8*)(&h1S[mh * 32 + rt * 16 + l15][ks * 32 + lg * 8]);
#pragma unroll
        for (int ct = 0; ct < 4; ++ct)
          Bw[ct] = *(const bs8*)(W2T + (fo + ct * 16 + l15) * 256 + c * 128 + ks * 32 + lg * 8);
#pragma unroll
        for (int ct = 0; ct < 4; ++ct)
#pragma unroll
          for (int rt = 0; rt < 2; ++rt)
            accL2[ct][rt] = MFMA16(Ah[rt], Bw[ct], accL2[ct][rt], 0, 0, 0);
      }
    }
    __syncthreads();  // done reading h1 chunk before overwrite
  }

  {  // L2 epilogue: pk gelu + mask + per-q row-sum -> staged
    const int fo = nh * 64;
    float psum[4];
#pragma unroll
    for (int ct = 0; ct < 4; ++ct) {
      float bias = b2[fo + ct * 16 + l15];
      float s = 0.0f;
#pragma unroll
      for (int rt = 0; rt < 2; ++rt) {
        f2 u0 = {accL2[ct][rt][0] + bias, accL2[ct][rt][1] + bias};
        f2 u1 = {accL2[ct][rt][2] + bias, accL2[ct][rt][3] + bias};
        f2 gA = gelu2(u0);
        f2 gB = gelu2(u1);
        int row = mh * 32 + rt * 16 + lg * 4;
        s += gA.x * maskfS[row] + gA.y * maskfS[row + 1] +
             gB.x * maskfS[row + 2] + gB.y * maskfS[row + 3];
      }
      psum[ct] = s;
    }
#pragma unroll
    for (int ct = 0; ct < 4; ++ct) {
      psum[ct] += __shfl_xor(psum[ct], 16, 64);
      psum[ct] += __shfl_xor(psum[ct], 32, 64);
    }
    if (lane < 16) {
      float* op = staged + ((size_t)((b << 12) + q0 + mh)) * 128 + fo;
      op[lane] = psum[0];
      op[16 + lane] = psum[1];
      op[32 + lane] = psum[2];
      op[48 + lane] = psum[3];
    }
  }
}

// fin2: out = h2sum @ W3 + cnt*b3 with transpose. 64 blocks: (b, hi, ct-half).
__global__ __launch_bounds__(256, 2) void gno_fin2(
    const float* __restrict__ staged, const float* __restrict__ cntG,
    const short* __restrict__ W3T, const float* __restrict__ b3,
    float* __restrict__ out) {
  __shared__ __align__(16) float tileS[16 * 260];
  __shared__ float cntS[256];
  __shared__ float b3S[128];
  const int tid = threadIdx.x, blk = blockIdx.x;
  const int b = blk >> 5;
  const int hi = (blk >> 1) & 15;
  const int q0 = hi * 256;
  const int ct0 = (blk & 1) * 4;
  cntS[tid] = cntG[(b << 12) + q0 + tid];
  if (tid < 128) b3S[tid] = b3[tid];
  __syncthreads();
  const int wid = tid >> 6, lane = tid & 63;
  const int l15 = lane & 15, lg = lane >> 4;
  const int r0 = wid * 64;
  f4 acc[4][4] = {};  // [c4][rt]; C: col=q(l15), row=feat(lg*4+i)
#pragma unroll
  for (int ks = 0; ks < 4; ++ks) {
    bs8 Aa[4];
#pragma unroll
    for (int rt = 0; rt < 4; ++rt) {
      const float* ap =
          staged + ((size_t)(b << 12) + q0 + r0 + rt * 16 + l15) * 128 + ks * 32 + lg * 8;
      f4 a0 = *(const f4*)ap;
      f4 a1 = *(const f4*)(ap + 4);
      uint4 uu;
      uu.x = pk2bf(a0[0], a0[1]);
      uu.y = pk2bf(a0[2], a0[3]);
      uu.z = pk2bf(a1[0], a1[1]);
      uu.w = pk2bf(a1[2], a1[3]);
      Aa[rt] = *reinterpret_cast<bs8*>(&uu);
    }
#pragma unroll
    for (int c4 = 0; c4 < 4; ++c4) {
      bs8 Bw = *(const bs8*)(W3T + ((ct0 + c4) * 16 + l15) * 128 + ks * 32 + lg * 8);
#pragma unroll
      for (int rt = 0; rt < 4; ++rt)
        acc[c4][rt] = MFMA16(Bw, Aa[rt], acc[c4][rt], 0, 0, 0);
    }
  }
#pragma unroll 1
  for (int c4 = 0; c4 < 4; ++c4) {
    int ct = ct0 + c4;
#pragma unroll
    for (int rt = 0; rt < 4; ++rt) {
      int rr = r0 + rt * 16 + l15;
      float cv = cntS[rr];
#pragma unroll
      for (int i = 0; i < 4; ++i) {
        int fl = lg * 4 + i;
        tileS[fl * 260 + rr] = acc[c4][rt][i] + cv * b3S[ct * 16 + fl];
      }
    }
    __syncthreads();
    {
      int fl = tid >> 4, dl = tid & 15;
      int o = ct * 16 + fl;
      float* dst = out + ((size_t)b << 19) + (o << 12) + (dl << 8) + (hi << 4);
#pragma unroll
      for (int w4 = 0; w4 < 4; ++w4) {
        float4 t;
        t.x = tileS[fl * 260 + (w4 * 4 + 0) * 16 + dl];
        t.y = tileS[fl * 260 + (w4 * 4 + 1) * 16 + dl];
        t.z = tileS[fl * 260 + (w4 * 4 + 2) * 16 + dl];
        t.w = tileS[fl * 260 + (w4 * 4 + 3) * 16 + dl];
        *(float4*)(dst + w4 * 4) = t;
      }
    }
    __syncthreads();
  }
}

// =================== old (fallback) path — round-1 kernels ===================

__global__ void gno_prep(const float* __restrict__ W0, const float* __restrict__ W1,
                         const float* __restrict__ W2, const float* __restrict__ W3,
                         short* __restrict__ W0aT, short* __restrict__ W1T,
                         short* __restrict__ W2T, short* __restrict__ W3T) {
  int g = blockIdx.x * 256 + threadIdx.x;
  if (g < 16384) {
    int n = g >> 7, k = g & 127;
    float v = (k < 96) ? W0[k * 128 + n] : ((k < 100) ? W0[(k + 96) * 128 + n] : 0.0f);
    W0aT[g] = f2bf(v);
  } else if (g < 49152) {
    int h = g - 16384, n = h >> 7, k = h & 127;
    W1T[h] = f2bf(W1[k * 256 + n]);
  } else if (g < 81920) {
    int h = g - 49152, n = h >> 8, k = h & 255;
    W2T[h] = f2bf(W2[k * 128 + n]);
  } else if (g < 98304) {
    int h = g - 81920, n = h >> 7, k = h & 127;
    W3T[h] = f2bf(W3[k * 128 + n]);
  }
}

template <int SIN, int K>
__device__ __forceinline__ void gemm_block(const short* inS, const short* __restrict__ WT,
                                           int colBase, int lane, f4 (&acc)[2][4]) {
  constexpr int KS = K / 32;
  bs8 Bf[2][KS];
  const int bcol = lane & 15;
  const int bk = (lane >> 4) * 8;
#pragma unroll
  for (int ct = 0; ct < 2; ++ct)
#pragma unroll
    for (int ks = 0; ks < KS; ++ks)
      Bf[ct][ks] = *reinterpret_cast<const bs8*>(WT + (colBase + ct * 16 + bcol) * K + ks * 32 + bk);
#pragma unroll
  for (int mt = 0; mt < 4; ++mt) {
#pragma unroll
    for (int ks = 0; ks < KS; ++ks) {
      bs8 Af = *reinterpret_cast<const bs8*>(inS + (mt * 16 + bcol) * SIN + ks * 32 + bk);
      acc[0][mt] = MFMA16(Af, Bf[0][ks], acc[0][mt], 0, 0, 0);
      acc[1][mt] = MFMA16(Af, Bf[1][ks], acc[1][mt], 0, 0, 0);
    }
  }
}

__global__ __launch_bounds__(256, 2) void gno_main(
    const float* __restrict__ x, const float* __restrict__ gc,
    const float* __restrict__ latg, const int* __restrict__ nidx,
    const float* __restrict__ W0, const float* __restrict__ b0,
    const float* __restrict__ b1, const float* __restrict__ b2,
    const float* __restrict__ b3,
    const short* __restrict__ W0aT, const short* __restrict__ W1T,
    const short* __restrict__ W2T, const short* __restrict__ W3T,
    float* __restrict__ dst, int direct) {
  __shared__ __align__(16) short aggS[64][136];
  __shared__ __align__(16) short h0S[64][136];
  __shared__ __align__(16) short h1S[64][264];
  __shared__ float vqS[2][128];
  __shared__ float maskfS[64];
  __shared__ float freqS[16];
  __shared__ float latS[2][3];
  __shared__ float sEmbQ[2][96];

  const int tid = threadIdx.x;
  const int blk = blockIdx.x;
  const int b = blk >> 11;
  const int q0 = (blk & 2047) * 2;

  if (tid < 16) freqS[tid] = (float)exp(-(double)tid * (9.210340371976184 / 16.0));
  if (tid >= 32 && tid < 38) {
    int t = tid - 32, qh = t / 3, a = t % 3;
    latS[qh][a] = latg[(q0 + qh) * 3 + a];
  }
  __syncthreads();
  if (tid < 192) {
    int qh = tid / 96, c = tid % 96, a = c >> 5, jj = c & 31;
    float ca = latS[qh][a];
    sEmbQ[qh][c] = (jj < 16) ? __sinf(ca * freqS[jj]) : __cosf(ca * freqS[jj & 15]);
  }
  __syncthreads();
  {
    int qh = tid >> 7, o = tid & 127;
    float s = b0[o];
#pragma unroll 4
    for (int j = 0; j < 96; ++j) s = fmaf(sEmbQ[qh][j], W0[(96 + j) * 128 + o], s);
    vqS[qh][o] = s;
  }
  {
    int r = tid >> 2, qq = tid & 3;
    int qh = r >> 5, kk = r & 31;
    int n = nidx[(q0 + qh) * 32 + kk];
    float c0 = gc[n * 3], c1 = gc[n * 3 + 1], c2 = gc[n * 3 + 2];
    if (qq == 0) {
      float d0 = __fsub_rn(latS[qh][0], c0);
      float d1 = __fsub_rn(latS[qh][1], c1);
      float d2 = __fsub_rn(latS[qh][2], c2);
      float s = __fadd_rn(__fadd_rn(__fmul_rn(d0, d0), __fmul_rn(d1, d1)), __fmul_rn(d2, d2));
      maskfS[r] = ((double)s <= 0.055 * 0.055) ? 1.0f : 0.0f;
    }
    float cc[3] = {c0, c1, c2};
    for (int c = qq * 34; c < qq * 34 + 34; ++c) {
      float v = 0.0f;
      if (c < 96) {
        int a = c >> 5, jj = c & 31;
        v = (jj < 16) ? __sinf(cc[a] * freqS[jj]) : __cosf(cc[a] * freqS[jj & 15]);
      } else if (c < 100) {
        int ch = c - 96;
        v = x[((b * 4 + ch) << 15) + ((n & 31) << 10) + (n >> 5)];
      }
      aggS[r][c] = f2bf(v);
    }
  }
  __syncthreads();

  const int wave = tid >> 6, lane = tid & 63;
  const int colBase = wave * 32;
  const int lrow4 = (lane >> 4) << 2;
  const int lcol = lane & 15;

  {
    f4 acc[2][4] = {};
    gemm_block<136, 128>(&aggS[0][0], W0aT, colBase, lane, acc);
#pragma unroll
    for (int ct = 0; ct < 2; ++ct) {
      int gcol = colBase + ct * 16 + lcol;
#pragma unroll
      for (int mt = 0; mt < 4; ++mt)
#pragma unroll
        for (int i = 0; i < 4; ++i) {
          int grow = mt * 16 + lrow4 + i;
          h0S[grow][gcol] = f2bf(gelu_old(acc[ct][mt][i] + vqS[grow >> 5][gcol]));
        }
    }
  }
  __syncthreads();
  {
#pragma unroll 1
    for (int cg = 0; cg < 2; ++cg) {
      int cb = wave * 64 + cg * 32;
      f4 acc[2][4] = {};
      gemm_block<136, 128>(&h0S[0][0], W1T, cb, lane, acc);
#pragma unroll
      for (int ct = 0; ct < 2; ++ct) {
        int gcol = cb + ct * 16 + lcol;
        float bias = b1[gcol];
#pragma unroll
        for (int mt = 0; mt < 4; ++mt)
#pragma unroll
          for (int i = 0; i < 4; ++i) {
            int grow = mt * 16 + lrow4 + i;
            h1S[grow][gcol] = f2bf(gelu_old(acc[ct][mt][i] + bias));
          }
      }
    }
  }
  __syncthreads();
  {
    f4 acc[2][4] = {};
    gemm_block<264, 256>(&h1S[0][0], W2T, colBase, lane, acc);
#pragma unroll
    for (int ct = 0; ct < 2; ++ct) {
      int gcol = colBase + ct * 16 + lcol;
      float bias = b2[gcol];
#pragma unroll
      for (int mt = 0; mt < 4; ++mt)
#pragma unroll
        for (int i = 0; i < 4; ++i) {
          int grow = mt * 16 + lrow4 + i;
          aggS[grow][gcol] = f2bf(gelu_old(acc[ct][mt][i] + bias));
        }
    }
  }
  __syncthreads();
  {
    f4 acc[2][4] = {};
    gemm_block<136, 128>(&aggS[0][0], W3T, colBase, lane, acc);
    float part[2][2] = {{0.0f, 0.0f}, {0.0f, 0.0f}};
#pragma unroll
    for (int ct = 0; ct < 2; ++ct) {
      float bias = b3[colBase + ct * 16 + lcol];
#pragma unroll
      for (int mt = 0; mt < 4; ++mt)
#pragma unroll
        for (int i = 0; i < 4; ++i) {
          int grow = mt * 16 + lrow4 + i;
          part[mt >> 1][ct] += (acc[ct][mt][i] + bias) * maskfS[grow];
        }
    }
#pragma unroll
    for (int qh = 0; qh < 2; ++qh)
#pragma unroll
      for (int ct = 0; ct < 2; ++ct) {
        float v = part[qh][ct];
        v += __shfl_xor(v, 16, 64);
        v += __shfl_xor(v, 32, 64);
        if (lane < 16) {
          int o = colBase + ct * 16 + lane;
          int q = q0 + qh;
          if (direct)
            dst[(b << 19) + (o << 12) + ((q & 15) << 8) + ((q >> 8) << 4) + ((q >> 4) & 15)] = v;
          else
            dst[(b * 4096 + q) * 128 + o] = v;
        }
      }
  }
}

__global__ void gno_tr(const float* __restrict__ staged, float* __restrict__ out) {
  __shared__ float tile[16][129];
  int blk = blockIdx.x;
  int b = blk >> 8, i = (blk >> 4) & 15, l = blk & 15;
  int t = threadIdx.x;
  {
    int j = t >> 4, oc = t & 15;
    const float* src = staged + ((b * 4096) + (i * 256 + j * 16 + l)) * 128 + oc * 8;
#pragma unroll
    for (int u = 0; u < 8; ++u) tile[j][oc * 8 + u] = src[u];
  }
  __syncthreads();
  {
    int og = t >> 4, j = t & 15;
#pragma unroll
    for (int oo = 0; oo < 8; ++oo) {
      int o = og * 8 + oo;
      out[(b << 19) + (o << 12) + (l << 8) + (i << 4) + j] = tile[j][o];
    }
  }
}

extern "C" void kernel_launch(void* const* d_in, const int* in_sizes, int n_in,
                              void* d_out, int out_size, void* d_ws, size_t ws_size,
                              hipStream_t stream) {
  const float* x    = (const float*)d_in[0];
  const float* gc   = (const float*)d_in[1];
  const float* latg = (const float*)d_in[2];
  const int*   nidx = (const int*)d_in[3];
  const float* W0 = (const float*)d_in[5];
  const float* b0 = (const float*)d_in[6];
  const float* W1 = (const float*)d_in[7];
  const float* b1 = (const float*)d_in[8];
  const float* W2 = (const float*)d_in[9];
  const float* b2 = (const float*)d_in[10];
  const float* W3 = (const float*)d_in[11];
  const float* b3 = (const float*)d_in[12];

  char* ws = (char*)d_ws;
  float* out = (float*)d_out;

  if (ws_size >= (size_t)FAST_NEED) {
    short* W1T  = (short*)(ws + W1T_OFF);
    short* W2T  = (short*)(ws + W2T_OFF);
    short* W3T  = (short*)(ws + W3T_OFF);
    short* W0eT = (short*)(ws + W0ET_OFF);
    short* W0mT = (short*)(ws + W0MT_OFF);
    float* vqPre = (float*)(ws + VQ_OFF);
    short* GF = (short*)(ws + GF_OFF);
    float* staged = (float*)(ws + ST_OFF);
    float* cntG = (float*)(ws + CNT_OFF);
    gno_prep3<<<416, 256, 0, stream>>>(W0, W1, W2, W3, W1T, W2T, W3T, W0eT, W0mT);
    gno_gfvq<<<576, 256, 0, stream>>>(x, gc, latg, W0, b0, W0eT, W0mT, GF, vqPre);
    gno_main5<<<4096, 256, 0, stream>>>(gc, latg, nidx, b1, b2,
                                        W1T, W2T, vqPre, GF, staged, cntG);
    gno_fin2<<<64, 256, 0, stream>>>(staged, cntG, W3T, b3, out);
  } else {
    short* W0aT = (short*)(ws + OW0AT_OFF);
    short* W1T  = (short*)(ws + OW1T_OFF);
    short* W2T  = (short*)(ws + OW2T_OFF);
    short* W3T  = (short*)(ws + OW3T_OFF);
    float* staged = (float*)(ws + OSTAGED_OFF);
    const bool use_staged = (ws_size >= (size_t)OLD_NEED);
    gno_prep<<<384, 256, 0, stream>>>(W0, W1, W2, W3, W0aT, W1T, W2T, W3T);
    gno_main<<<4096, 256, 0, stream>>>(x, gc, latg, nidx, W0, b0, b1, b2, b3,
                                       W0aT, W1T, W2T, W3T,
                                       use_staged ? staged : out, use_staged ? 0 : 1);
    if (use_staged) gno_tr<<<512, 256, 0, stream>>>(staged, out);
  }
}

// Round 7
// 226.826 us; speedup vs baseline: 1.2543x; 1.0658x over previous
//
#include <hip/hip_runtime.h>
#include <hip/hip_bf16.h>
#include <math.h>

// GNO stem, round 7: 2 launches (was 4). Launch-gap model: ~25-30us per kernel
// boundary (consistent across r1-r6).
//  - gno_aux (896 blk): [0,512) GF units (self-stage W0[0:96]->LDS bf16, R4-proven),
//    [512,576) vq units (self-stage W0[96:192], MFMA), [576,896) W1/W2/W3 transposes.
//    No inter-kernel dependency -> prep launch eliminated.
//  - gno_main6: main5 + fused W3 epilogue: masked h2-sum -> LDS bf16 rows (2 valid of
//    16; garbage rows safe, MFMA C-rows independent) -> 8 MFMA/wave vs W3T -> direct
//    transposed out stores with cnt*b3. staged/cntG/fin2 eliminated.

typedef short bs8 __attribute__((ext_vector_type(8)));
typedef float f4  __attribute__((ext_vector_type(4)));
typedef float f2  __attribute__((ext_vector_type(2)));

#define MFMA16 __builtin_amdgcn_mfma_f32_16x16x32_bf16

// ---------- fast-path ws layout (bytes) ----------
#define W1T_OFF    0u          // [256][128] bf16  65536
#define W2T_OFF    65536u      // [128][256] bf16  65536
#define W3T_OFF    131072u     // [128][128] bf16  32768
#define VQ_OFF     212992u     // [4096][128] f32  2097152
#define GF_OFF     2310144u    // [2][32768][128] bf16 16777216
#define FAST_NEED  23314432u

// ---------- old-path ws layout ----------
#define OW0AT_OFF   0
#define OW1T_OFF    32768
#define OW2T_OFF    98304
#define OW3T_OFF    163840
#define OSTAGED_OFF 196608
#define OLD_NEED    (196608 + 4194304)

__device__ __forceinline__ short f2bf(float f) {
  unsigned u = __float_as_uint(f);
  return (short)((u + 0x7FFFu + ((u >> 16) & 1u)) >> 16);  // RNE
}
__device__ __forceinline__ float bf2f(short s) {
  return __uint_as_float(((unsigned)(unsigned short)s) << 16);
}
__device__ __forceinline__ unsigned pk2bf(float lo, float hi) {
  __hip_bfloat162 h = __float22bfloat162_rn(float2{lo, hi});  // v_cvt_pk_bf16_f32
  return *reinterpret_cast<unsigned*>(&h);
}
// packed gelu: x - x/(1+E), E = 2^(x*(a + a*0.044715*x^2)).
__device__ __forceinline__ f2 gelu2(f2 x) {
  f2 t = x * x;
  f2 z = x * (t * 0.10294322f + 2.3022077f);
  f2 e;
  e.x = __builtin_exp2f(z.x);
  e.y = __builtin_exp2f(z.y);
  f2 d = e + 1.0f;
  f2 r;
  r.x = __builtin_amdgcn_rcpf(d.x);
  r.y = __builtin_amdgcn_rcpf(d.y);
  return x - x * r;
}
__device__ __forceinline__ float gelu_old(float x) {
  float z = 0.7978845608028654f * fmaf(0.044715f * x, x * x, x);
  float e = __expf(2.0f * z);
  return 0.5f * x * (2.0f - 2.0f / (e + 1.0f));
}

// =================== fast path ===================

// aux: [0,512) GF units; [512,576) vq units; [576,896) weight transposes.
__global__ __launch_bounds__(256, 3) void gno_aux(
    const float* __restrict__ x, const float* __restrict__ gc,
    const float* __restrict__ latg, const float* __restrict__ W0,
    const float* __restrict__ b0,
    const float* __restrict__ W1, const float* __restrict__ W2,
    const float* __restrict__ W3,
    short* __restrict__ W1T, short* __restrict__ W2T, short* __restrict__ W3T,
    short* __restrict__ GF, float* __restrict__ vqPre) {
  __shared__ __align__(16) short w0S[128 * 104];   // 26624 B; reused as tileS
  __shared__ __align__(16) short embS[64 * 104];   // 13312 B
  __shared__ float gcS[192];
  __shared__ float xS[8][64];                      // [b*4+ch][pt] (GF only)
  __shared__ float wfS[4][128];                    // (GF only)
  __shared__ float freqS[16];
  short* tileS = w0S;                              // [64][132] after MFMA (GF only)

  const int tid = threadIdx.x;
  const int u = blockIdx.x;

  if (u >= 576) {  // ---- weight transposes: 81920 elems over 320 blocks ----
    int g = (u - 576) * 256 + tid;
    if (g < 32768) {            // W1T [n=256][k=128]
      int nn = g >> 7, k = g & 127;
      W1T[g] = f2bf(W1[k * 256 + nn]);
    } else if (g < 65536) {     // W2T [n=128][k=256]
      int h = g - 32768, nn = h >> 8, k = h & 255;
      W2T[h] = f2bf(W2[k * 128 + nn]);
    } else {                    // W3T [n=128][k=128]
      int h = g - 65536, nn = h >> 7, k = h & 127;
      W3T[h] = f2bf(W3[k * 128 + nn]);
    }
    return;
  }

  const bool isGF = u < 512;
  const int p0 = isGF ? u * 64 : (u - 512) * 64;
  const int kbase = isGF ? 0 : 96;

  // self-stage W0 slice -> w0S bf16 [f(128)][k pad 104]; coalesced global reads
  for (int e = tid; e < 12288; e += 256) {
    int k = e >> 7, f = e & 127;
    w0S[f * 104 + k] = f2bf(W0[kbase * 128 + e]);
  }
  if (tid < 16) freqS[tid] = (float)exp(-(double)tid * (9.210340371976184 / 16.0));
  if (tid < 192) gcS[tid] = isGF ? gc[p0 * 3 + tid] : latg[p0 * 3 + tid];
  if (isGF) {
#pragma unroll
    for (int uu = 0; uu < 2; ++uu) {
      int slot = tid * 2 + uu;  // 512 slots
      int bb = slot >> 8, ch = (slot >> 6) & 3, i = slot & 63;
      int n = p0 + i;
      xS[bb * 4 + ch][i] = x[((bb * 4 + ch) << 15) + ((n & 31) << 10) + (n >> 5)];
      wfS[slot >> 7][slot & 127] = W0[(192 + (slot >> 7)) * 128 + (slot & 127)];
    }
  }
  __syncthreads();
  {  // embedding trig: 64 rows x 96 cols
    int rr = tid >> 2, c4 = tid & 3;
#pragma unroll
    for (int c = c4 * 24; c < c4 * 24 + 24; ++c) {
      int a = c >> 5, jj = c & 31;
      float v = (jj < 16) ? __sinf(gcS[rr * 3 + a] * freqS[jj])
                          : __cosf(gcS[rr * 3 + a] * freqS[jj & 15]);
      embS[rr * 104 + c] = f2bf(v);
    }
  }
  __syncthreads();
  const int wid = tid >> 6, lane = tid & 63;
  const int l15 = lane & 15, lg = lane >> 4;
  const int f0 = wid * 32;
  f4 acc[2][4] = {};  // [ftile][ptile]; C: col=point(l15), row=feat(lg*4+i)
#pragma unroll
  for (int ks = 0; ks < 3; ++ks) {
    bs8 Aw[2], Be[4];
#pragma unroll
    for (int ft = 0; ft < 2; ++ft)
      Aw[ft] = *(const bs8*)(w0S + (f0 + ft * 16 + l15) * 104 + ks * 32 + lg * 8);
#pragma unroll
    for (int pt = 0; pt < 4; ++pt)
      Be[pt] = *(const bs8*)(embS + (pt * 16 + l15) * 104 + ks * 32 + lg * 8);
#pragma unroll
    for (int ft = 0; ft < 2; ++ft)
#pragma unroll
      for (int pt = 0; pt < 4; ++pt)
        acc[ft][pt] = MFMA16(Aw[ft], Be[pt], acc[ft][pt], 0, 0, 0);
  }
  if (!isGF) {  // vq epilogue: vqPre[q][f] = acc + b0[f], f32
#pragma unroll
    for (int ft = 0; ft < 2; ++ft) {
      f4 bias = *(const f4*)(b0 + f0 + ft * 16 + lg * 4);
#pragma unroll
      for (int pt = 0; pt < 4; ++pt) {
        int q = p0 + pt * 16 + l15;
        *(f4*)(vqPre + q * 128 + f0 + ft * 16 + lg * 4) = acc[ft][pt] + bias;
      }
    }
    return;
  }
  __syncthreads();  // w0S fragment reads complete -> tileS overwrite safe
#pragma unroll 1
  for (int bb = 0; bb < 2; ++bb) {
#pragma unroll
    for (int ft = 0; ft < 2; ++ft) {
      f4 wf0 = *(const f4*)(&wfS[0][f0 + ft * 16 + lg * 4]);
      f4 wf1 = *(const f4*)(&wfS[1][f0 + ft * 16 + lg * 4]);
      f4 wf2 = *(const f4*)(&wfS[2][f0 + ft * 16 + lg * 4]);
      f4 wf3 = *(const f4*)(&wfS[3][f0 + ft * 16 + lg * 4]);
#pragma unroll
      for (int pt = 0; pt < 4; ++pt) {
        int p = pt * 16 + l15;
        float x0 = xS[bb * 4 + 0][p], x1 = xS[bb * 4 + 1][p];
        float x2 = xS[bb * 4 + 2][p], x3 = xS[bb * 4 + 3][p];
        float v0 = acc[ft][pt][0] + x0 * wf0[0] + x1 * wf1[0] + x2 * wf2[0] + x3 * wf3[0];
        float v1 = acc[ft][pt][1] + x0 * wf0[1] + x1 * wf1[1] + x2 * wf2[1] + x3 * wf3[1];
        float v2 = acc[ft][pt][2] + x0 * wf0[2] + x1 * wf1[2] + x2 * wf2[2] + x3 * wf3[2];
        float v3 = acc[ft][pt][3] + x0 * wf0[3] + x1 * wf1[3] + x2 * wf2[3] + x3 * wf3[3];
        uint2 pp;
        pp.x = pk2bf(v0, v1);
        pp.y = pk2bf(v2, v3);
        *(uint2*)(tileS + p * 132 + f0 + ft * 16 + lg * 4) = pp;
      }
    }
    __syncthreads();
    {  // coalesced copy-out: 64 rows x 256B
      int row = tid >> 2, c4 = tid & 3;
      const short* src = tileS + row * 132 + c4 * 32;
      short* dst = GF + ((size_t)((bb << 15) + p0 + row)) * 128 + c4 * 32;
      *(uint4*)(dst)      = *(const uint4*)(src);
      *(uint4*)(dst + 8)  = *(const uint4*)(src + 8);
      *(uint4*)(dst + 16) = *(const uint4*)(src + 16);
      *(uint4*)(dst + 24) = *(const uint4*)(src + 24);
    }
    __syncthreads();
  }
}

// h0: gelu(GF + vq) for 8 bf16 packed in a uint4, fully pk.
__device__ __forceinline__ uint4 gelu8u(uint4 gu, const float* vrow) {
  uint4 r;
  const unsigned ua[4] = {gu.x, gu.y, gu.z, gu.w};
  unsigned ro[4];
#pragma unroll
  for (int j = 0; j < 4; ++j) {
    f2 xx;
    xx.x = __uint_as_float(ua[j] << 16);
    xx.y = __uint_as_float(ua[j] & 0xFFFF0000u);
    xx += *(const f2*)(vrow + 2 * j);
    f2 g = gelu2(xx);
    ro[j] = pk2bf(g.x, g.y);
  }
  r.x = ro[0]; r.y = ro[1]; r.z = ro[2]; r.w = ro[3];
  return r;
}

// main6: block = (b, 2 q) = 64 rows; 4 waves; h1 in 2x128-col chunks; fused W3.
__global__ __launch_bounds__(256, 4) void gno_main6(
    const float* __restrict__ gc, const float* __restrict__ latg,
    const int* __restrict__ nidx,
    const float* __restrict__ b1, const float* __restrict__ b2,
    const float* __restrict__ b3,
    const short* __restrict__ W1T, const short* __restrict__ W2T,
    const short* __restrict__ W3T,
    const float* __restrict__ vqPre, const short* __restrict__ GF,
    float* __restrict__ out) {
  __shared__ __align__(16) short h0S[64][136];   // reused: rows 0..15 = h2b
  __shared__ __align__(16) short h1S[64][136];
  __shared__ float vqS[2][128];
  __shared__ float maskfS[64];
  __shared__ float b3S[128];
  __shared__ float cntS[2];

  const int tid = threadIdx.x;
  const int blk = blockIdx.x;
  const int b = blk >> 11;
  const int q0 = (blk & 2047) * 2;

  vqS[tid >> 7][tid & 127] = vqPre[(q0 + (tid >> 7)) * 128 + (tid & 127)];
  if (tid < 128) b3S[tid] = b3[tid];

  const int r = tid >> 2, seg = tid & 3;
  const int qh = r >> 5;
  const int n = nidx[(q0 + qh) * 32 + (r & 31)];
  const uint4* gp = (const uint4*)(GF + ((size_t)((b << 15) + n)) * 128 + seg * 32);
  uint4 g0 = gp[0], g1 = gp[1], g2 = gp[2], g3 = gp[3];
  if (seg == 0) {  // exact mask (fp32 arith, double cmp — replicates setup bit-exactly)
    float la = latg[(q0 + qh) * 3], lb = latg[(q0 + qh) * 3 + 1], lc = latg[(q0 + qh) * 3 + 2];
    float d0 = __fsub_rn(la, gc[n * 3]);
    float d1 = __fsub_rn(lb, gc[n * 3 + 1]);
    float d2 = __fsub_rn(lc, gc[n * 3 + 2]);
    float s = __fadd_rn(__fadd_rn(__fmul_rn(d0, d0), __fmul_rn(d1, d1)), __fmul_rn(d2, d2));
    maskfS[r] = ((double)s <= 0.055 * 0.055) ? 1.0f : 0.0f;
  }
  __syncthreads();  // vqS ready
  {  // h0 = gelu(GF + vq)
    const float* vrow = vqS[qh] + seg * 32;
    *(uint4*)(&h0S[r][seg * 32]) = gelu8u(g0, vrow);
    *(uint4*)(&h0S[r][seg * 32 + 8]) = gelu8u(g1, vrow + 8);
    *(uint4*)(&h0S[r][seg * 32 + 16]) = gelu8u(g2, vrow + 16);
    *(uint4*)(&h0S[r][seg * 32 + 24]) = gelu8u(g3, vrow + 24);
  }
  __syncthreads();  // h0S + mask ready
  if (tid < 2) {  // neighbor count per q (read after next barrier)
    float s = 0.0f;
#pragma unroll
    for (int i = 0; i < 32; ++i) s += maskfS[tid * 32 + i];
    cntS[tid] = s;
  }

  const int wid = tid >> 6, lane = tid & 63;
  const int l15 = lane & 15, lg = lane >> 4;
  const int mh = wid >> 1, nh = wid & 1;  // L2 roles
  f4 accL2[4][2] = {};                    // persists across chunks

#pragma unroll 1
  for (int c = 0; c < 2; ++c) {
    {  // L1 chunk: wave owns 32 feats x all 64 rows
      const int f0l = wid * 32;
      const int fg = c * 128 + f0l;
      f4 acc[2][4] = {};
#pragma unroll
      for (int ks = 0; ks < 4; ++ks) {
        bs8 Aw[2], Bh[4];
#pragma unroll
        for (int ft = 0; ft < 2; ++ft)
          Aw[ft] = *(const bs8*)(W1T + (fg + ft * 16 + l15) * 128 + ks * 32 + lg * 8);
#pragma unroll
        for (int rt = 0; rt < 4; ++rt)
          Bh[rt] = *(const bs8*)(&h0S[rt * 16 + l15][ks * 32 + lg * 8]);
#pragma unroll
        for (int ft = 0; ft < 2; ++ft)
#pragma unroll
          for (int rt = 0; rt < 4; ++rt)
            acc[ft][rt] = MFMA16(Aw[ft], Bh[rt], acc[ft][rt], 0, 0, 0);
      }
#pragma unroll
      for (int ft = 0; ft < 2; ++ft) {
        f4 bias = *(const f4*)(b1 + fg + ft * 16 + lg * 4);
#pragma unroll
        for (int rt = 0; rt < 4; ++rt) {
          f2 a = {acc[ft][rt][0] + bias[0], acc[ft][rt][1] + bias[1]};
          f2 bpair = {acc[ft][rt][2] + bias[2], acc[ft][rt][3] + bias[3]};
          f2 ga = gelu2(a);
          f2 gb = gelu2(bpair);
          uint2 p;
          p.x = pk2bf(ga.x, ga.y);
          p.y = pk2bf(gb.x, gb.y);
          *(uint2*)(&h1S[rt * 16 + l15][f0l + ft * 16 + lg * 4]) = p;
        }
      }
    }
    __syncthreads();  // h1 chunk ready
    {  // L2 partial-K accumulate: wave (mh: 32 rows) x (nh: 64 out-feats)
      const int fo = nh * 64;
#pragma unroll
      for (int ks = 0; ks < 4; ++ks) {
        bs8 Ah[2], Bw[4];
#pragma unroll
        for (int rt = 0; rt < 2; ++rt)
          Ah[rt] = *(const bs8*)(&h1S[mh * 32 + rt * 16 + l15][ks * 32 + lg * 8]);
#pragma unroll
        for (int ct = 0; ct < 4; ++ct)
          Bw[ct] = *(const bs8*)(W2T + (fo + ct * 16 + l15) * 256 + c * 128 + ks * 32 + lg * 8);
#pragma unroll
        for (int ct = 0; ct < 4; ++ct)
#pragma unroll
          for (int rt = 0; rt < 2; ++rt)
            accL2[ct][rt] = MFMA16(Ah[rt], Bw[ct], accL2[ct][rt], 0, 0, 0);
      }
    }
    __syncthreads();  // done reading h1 chunk before overwrite
  }

  {  // L2 epilogue: pk gelu + mask + per-q row-sum -> h2b (h0S rows 0,1) bf16
    const int fo = nh * 64;
    float psum[4];
#pragma unroll
    for (int ct = 0; ct < 4; ++ct) {
      float bias = b2[fo + ct * 16 + l15];
      float s = 0.0f;
#pragma unroll
      for (int rt = 0; rt < 2; ++rt) {
        f2 u0 = {accL2[ct][rt][0] + bias, accL2[ct][rt][1] + bias};
        f2 u1 = {accL2[ct][rt][2] + bias, accL2[ct][rt][3] + bias};
        f2 gA = gelu2(u0);
        f2 gB = gelu2(u1);
        int row = mh * 32 + rt * 16 + lg * 4;
        s += gA.x * maskfS[row] + gA.y * maskfS[row + 1] +
             gB.x * maskfS[row + 2] + gB.y * maskfS[row + 3];
      }
      psum[ct] = s;
    }
#pragma unroll
    for (int ct = 0; ct < 4; ++ct) {
      psum[ct] += __shfl_xor(psum[ct], 16, 64);
      psum[ct] += __shfl_xor(psum[ct], 32, 64);
    }
    if (lane < 16) {
#pragma unroll
      for (int ct = 0; ct < 4; ++ct)
        h0S[mh][fo + ct * 16 + lane] = f2bf(psum[ct]);
    }
  }
  __syncthreads();  // h2b ready (rows 0,1 of h0S; rows 2..15 stale-but-finite)
  {  // fused W3: out = h2b @ W3 + cnt*b3, direct transposed store
    const int wf = wid * 32;
    f4 a3[2] = {};  // [ct2]; C: col=l15 (feat), row=lg*4+i (q-row; only 0,1 valid)
#pragma unroll
    for (int ks = 0; ks < 4; ++ks) {
      bs8 Ah = *(const bs8*)(&h0S[l15][ks * 32 + lg * 8]);
#pragma unroll
      for (int ct2 = 0; ct2 < 2; ++ct2) {
        bs8 Bw = *(const bs8*)(W3T + (wf + ct2 * 16 + l15) * 128 + ks * 32 + lg * 8);
        a3[ct2] = MFMA16(Ah, Bw, a3[ct2], 0, 0, 0);
      }
    }
    if (lg == 0) {
#pragma unroll
      for (int ct2 = 0; ct2 < 2; ++ct2) {
        int feat = wf + ct2 * 16 + l15;
        float bb3 = b3S[feat];
#pragma unroll
        for (int i = 0; i < 2; ++i) {
          int q = q0 + i;
          out[(b << 19) + (feat << 12) + ((q & 15) << 8) + ((q >> 8) << 4) +
              ((q >> 4) & 15)] = a3[ct2][i] + cntS[i] * bb3;
        }
      }
    }
  }
}

// =================== old (fallback) path — round-1 kernels ===================

__global__ void gno_prep(const float* __restrict__ W0, const float* __restrict__ W1,
                         const float* __restrict__ W2, const float* __restrict__ W3,
                         short* __restrict__ W0aT, short* __restrict__ W1T,
                         short* __restrict__ W2T, short* __restrict__ W3T) {
  int g = blockIdx.x * 256 + threadIdx.x;
  if (g < 16384) {
    int n = g >> 7, k = g & 127;
    float v = (k < 96) ? W0[k * 128 + n] : ((k < 100) ? W0[(k + 96) * 128 + n] : 0.0f);
    W0aT[g] = f2bf(v);
  } else if (g < 49152) {
    int h = g - 16384, n = h >> 7, k = h & 127;
    W1T[h] = f2bf(W1[k * 256 + n]);
  } else if (g < 81920) {
    int h = g - 49152, n = h >> 8, k = h & 255;
    W2T[h] = f2bf(W2[k * 128 + n]);
  } else if (g < 98304) {
    int h = g - 81920, n = h >> 7, k = h & 127;
    W3T[h] = f2bf(W3[k * 128 + n]);
  }
}

template <int SIN, int K>
__device__ __forceinline__ void gemm_block(const short* inS, const short* __restrict__ WT,
                                           int colBase, int lane, f4 (&acc)[2][4]) {
  constexpr int KS = K / 32;
  bs8 Bf[2][KS];
  const int bcol = lane & 15;
  const int bk = (lane >> 4) * 8;
#pragma unroll
  for (int ct = 0; ct < 2; ++ct)
#pragma unroll
    for (int ks = 0; ks < KS; ++ks)
      Bf[ct][ks] = *reinterpret_cast<const bs8*>(WT + (colBase + ct * 16 + bcol) * K + ks * 32 + bk);
#pragma unroll
  for (int mt = 0; mt < 4; ++mt) {
#pragma unroll
    for (int ks = 0; ks < KS; ++ks) {
      bs8 Af = *reinterpret_cast<const bs8*>(inS + (mt * 16 + bcol) * SIN + ks * 32 + bk);
      acc[0][mt] = MFMA16(Af, Bf[0][ks], acc[0][mt], 0, 0, 0);
      acc[1][mt] = MFMA16(Af, Bf[1][ks], acc[1][mt], 0, 0, 0);
    }
  }
}

__global__ __launch_bounds__(256, 2) void gno_main(
    const float* __restrict__ x, const float* __restrict__ gc,
    const float* __restrict__ latg, const int* __restrict__ nidx,
    const float* __restrict__ W0, const float* __restrict__ b0,
    const float* __restrict__ b1, const float* __restrict__ b2,
    const float* __restrict__ b3,
    const short* __restrict__ W0aT, const short* __restrict__ W1T,
    const short* __restrict__ W2T, const short* __restrict__ W3T,
    float* __restrict__ dst, int direct) {
  __shared__ __align__(16) short aggS[64][136];
  __shared__ __align__(16) short h0S[64][136];
  __shared__ __align__(16) short h1S[64][264];
  __shared__ float vqS[2][128];
  __shared__ float maskfS[64];
  __shared__ float freqS[16];
  __shared__ float latS[2][3];
  __shared__ float sEmbQ[2][96];

  const int tid = threadIdx.x;
  const int blk = blockIdx.x;
  const int b = blk >> 11;
  const int q0 = (blk & 2047) * 2;

  if (tid < 16) freqS[tid] = (float)exp(-(double)tid * (9.210340371976184 / 16.0));
  if (tid >= 32 && tid < 38) {
    int t = tid - 32, qh = t / 3, a = t % 3;
    latS[qh][a] = latg[(q0 + qh) * 3 + a];
  }
  __syncthreads();
  if (tid < 192) {
    int qh = tid / 96, c = tid % 96, a = c >> 5, jj = c & 31;
    float ca = latS[qh][a];
    sEmbQ[qh][c] = (jj < 16) ? __sinf(ca * freqS[jj]) : __cosf(ca * freqS[jj & 15]);
  }
  __syncthreads();
  {
    int qh = tid >> 7, o = tid & 127;
    float s = b0[o];
#pragma unroll 4
    for (int j = 0; j < 96; ++j) s = fmaf(sEmbQ[qh][j], W0[(96 + j) * 128 + o], s);
    vqS[qh][o] = s;
  }
  {
    int r = tid >> 2, qq = tid & 3;
    int qh = r >> 5, kk = r & 31;
    int n = nidx[(q0 + qh) * 32 + kk];
    float c0 = gc[n * 3], c1 = gc[n * 3 + 1], c2 = gc[n * 3 + 2];
    if (qq == 0) {
      float d0 = __fsub_rn(latS[qh][0], c0);
      float d1 = __fsub_rn(latS[qh][1], c1);
      float d2 = __fsub_rn(latS[qh][2], c2);
      float s = __fadd_rn(__fadd_rn(__fmul_rn(d0, d0), __fmul_rn(d1, d1)), __fmul_rn(d2, d2));
      maskfS[r] = ((double)s <= 0.055 * 0.055) ? 1.0f : 0.0f;
    }
    float cc[3] = {c0, c1, c2};
    for (int c = qq * 34; c < qq * 34 + 34; ++c) {
      float v = 0.0f;
      if (c < 96) {
        int a = c >> 5, jj = c & 31;
        v = (jj < 16) ? __sinf(cc[a] * freqS[jj]) : __cosf(cc[a] * freqS[jj & 15]);
      } else if (c < 100) {
        int ch = c - 96;
        v = x[((b * 4 + ch) << 15) + ((n & 31) << 10) + (n >> 5)];
      }
      aggS[r][c] = f2bf(v);
    }
  }
  __syncthreads();

  const int wave = tid >> 6, lane = tid & 63;
  const int colBase = wave * 32;
  const int lrow4 = (lane >> 4) << 2;
  const int lcol = lane & 15;

  {
    f4 acc[2][4] = {};
    gemm_block<136, 128>(&aggS[0][0], W0aT, colBase, lane, acc);
#pragma unroll
    for (int ct = 0; ct < 2; ++ct) {
      int gcol = colBase + ct * 16 + lcol;
#pragma unroll
      for (int mt = 0; mt < 4; ++mt)
#pragma unroll
        for (int i = 0; i < 4; ++i) {
          int grow = mt * 16 + lrow4 + i;
          h0S[grow][gcol] = f2bf(gelu_old(acc[ct][mt][i] + vqS[grow >> 5][gcol]));
        }
    }
  }
  __syncthreads();
  {
#pragma unroll 1
    for (int cg = 0; cg < 2; ++cg) {
      int cb = wave * 64 + cg * 32;
      f4 acc[2][4] = {};
      gemm_block<136, 128>(&h0S[0][0], W1T, cb, lane, acc);
#pragma unroll
      for (int ct = 0; ct < 2; ++ct) {
        int gcol = cb + ct * 16 + lcol;
        float bias = b1[gcol];
#pragma unroll
        for (int mt = 0; mt < 4; ++mt)
#pragma unroll
          for (int i = 0; i < 4; ++i) {
            int grow = mt * 16 + lrow4 + i;
            h1S[grow][gcol] = f2bf(gelu_old(acc[ct][mt][i] + bias));
          }
      }
    }
  }
  __syncthreads();
  {
    f4 acc[2][4] = {};
    gemm_block<264, 256>(&h1S[0][0], W2T, colBase, lane, acc);
#pragma unroll
    for (int ct = 0; ct < 2; ++ct) {
      int gcol = colBase + ct * 16 + lcol;
      float bias = b2[gcol];
#pragma unroll
      for (int mt = 0; mt < 4; ++mt)
#pragma unroll
        for (int i = 0; i < 4; ++i) {
          int grow = mt * 16 + lrow4 + i;
          aggS[grow][gcol] = f2bf(gelu_old(acc[ct][mt][i] + bias));
        }
    }
  }
  __syncthreads();
  {
    f4 acc[2][4] = {};
    gemm_block<136, 128>(&aggS[0][0], W3T, colBase, lane, acc);
    float part[2][2] = {{0.0f, 0.0f}, {0.0f, 0.0f}};
#pragma unroll
    for (int ct = 0; ct < 2; ++ct) {
      float bias = b3[colBase + ct * 16 + lcol];
#pragma unroll
      for (int mt = 0; mt < 4; ++mt)
#pragma unroll
        for (int i = 0; i < 4; ++i) {
          int grow = mt * 16 + lrow4 + i;
          part[mt >> 1][ct] += (acc[ct][mt][i] + bias) * maskfS[grow];
        }
    }
#pragma unroll
    for (int qh = 0; qh < 2; ++qh)
#pragma unroll
      for (int ct = 0; ct < 2; ++ct) {
        float v = part[qh][ct];
        v += __shfl_xor(v, 16, 64);
        v += __shfl_xor(v, 32, 64);
        if (lane < 16) {
          int o = colBase + ct * 16 + lane;
          int q = q0 + qh;
          if (direct)
            dst[(b << 19) + (o << 12) + ((q & 15) << 8) + ((q >> 8) << 4) + ((q >> 4) & 15)] = v;
          else
            dst[(b * 4096 + q) * 128 + o] = v;
        }
      }
  }
}

__global__ void gno_tr(const float* __restrict__ staged, float* __restrict__ out) {
  __shared__ float tile[16][129];
  int blk = blockIdx.x;
  int b = blk >> 8, i = (blk >> 4) & 15, l = blk & 15;
  int t = threadIdx.x;
  {
    int j = t >> 4, oc = t & 15;
    const float* src = staged + ((b * 4096) + (i * 256 + j * 16 + l)) * 128 + oc * 8;
#pragma unroll
    for (int u = 0; u < 8; ++u) tile[j][oc * 8 + u] = src[u];
  }
  __syncthreads();
  {
    int og = t >> 4, j = t & 15;
#pragma unroll
    for (int oo = 0; oo < 8; ++oo) {
      int o = og * 8 + oo;
      out[(b << 19) + (o << 12) + (l << 8) + (i << 4) + j] = tile[j][o];
    }
  }
}

extern "C" void kernel_launch(void* const* d_in, const int* in_sizes, int n_in,
                              void* d_out, int out_size, void* d_ws, size_t ws_size,
                              hipStream_t stream) {
  const float* x    = (const float*)d_in[0];
  const float* gc   = (const float*)d_in[1];
  const float* latg = (const float*)d_in[2];
  const int*   nidx = (const int*)d_in[3];
  const float* W0 = (const float*)d_in[5];
  const float* b0 = (const float*)d_in[6];
  const float* W1 = (const float*)d_in[7];
  const float* b1 = (const float*)d_in[8];
  const float* W2 = (const float*)d_in[9];
  const float* b2 = (const float*)d_in[10];
  const float* W3 = (const float*)d_in[11];
  const float* b3 = (const float*)d_in[12];

  char* ws = (char*)d_ws;
  float* out = (float*)d_out;

  if (ws_size >= (size_t)FAST_NEED) {
    short* W1T  = (short*)(ws + W1T_OFF);
    short* W2T  = (short*)(ws + W2T_OFF);
    short* W3T  = (short*)(ws + W3T_OFF);
    float* vqPre = (float*)(ws + VQ_OFF);
    short* GF = (short*)(ws + GF_OFF);
    gno_aux<<<896, 256, 0, stream>>>(x, gc, latg, W0, b0, W1, W2, W3,
                                     W1T, W2T, W3T, GF, vqPre);
    gno_main6<<<4096, 256, 0, stream>>>(gc, latg, nidx, b1, b2, b3,
                                        W1T, W2T, W3T, vqPre, GF, out);
  } else {
    short* W0aT = (short*)(ws + OW0AT_OFF);
    short* W1T  = (short*)(ws + OW1T_OFF);
    short* W2T  = (short*)(ws + OW2T_OFF);
    short* W3T  = (short*)(ws + OW3T_OFF);
    float* staged = (float*)(ws + OSTAGED_OFF);
    const bool use_staged = (ws_size >= (size_t)OLD_NEED);
    gno_prep<<<384, 256, 0, stream>>>(W0, W1, W2, W3, W0aT, W1T, W2T, W3T);
    gno_main<<<4096, 256, 0, stream>>>(x, gc, latg, nidx, W0, b0, b1, b2, b3,
                                       W0aT, W1T, W2T, W3T,
                                       use_staged ? staged : out, use_staged ? 0 : 1);
    if (use_staged) gno_tr<<<512, 256, 0, stream>>>(staged, out);
  }
}

// Round 8
// 220.217 us; speedup vs baseline: 1.2920x; 1.0300x over previous
//
#include <hip/hip_runtime.h>
#include <hip/hip_bf16.h>
#include <math.h>

// GNO stem, round 8.
//  - main7: block = 4 q = 128 rows, 512 thr / 8 waves, 2048 blocks. Halves
//    barrier-phases per row, halves weight L2 traffic, occupancy 41->50%.
//    W3 stays fused (4 valid h2b rows).
//  - aux2: trig via 32-value coord table (grid axes are all linspace(0,1,32) ->
//    1024 trig/block instead of 6144); GF written with direct uint2 stores
//    (r3-proven), tile-transpose stage dropped.
//  - 2 launches: aux2 -> main7.

typedef short bs8 __attribute__((ext_vector_type(8)));
typedef float f4  __attribute__((ext_vector_type(4)));
typedef float f2  __attribute__((ext_vector_type(2)));

#define MFMA16 __builtin_amdgcn_mfma_f32_16x16x32_bf16

// ---------- fast-path ws layout (bytes) ----------
#define W1T_OFF    0u          // [256][128] bf16  65536
#define W2T_OFF    65536u      // [128][256] bf16  65536
#define W3T_OFF    131072u     // [128][128] bf16  32768
#define VQ_OFF     212992u     // [4096][128] f32  2097152
#define GF_OFF     2310144u    // [2][32768][128] bf16 16777216
#define FAST_NEED  23314432u

// ---------- old-path ws layout ----------
#define OW0AT_OFF   0
#define OW1T_OFF    32768
#define OW2T_OFF    98304
#define OW3T_OFF    163840
#define OSTAGED_OFF 196608
#define OLD_NEED    (196608 + 4194304)

__device__ __forceinline__ short f2bf(float f) {
  unsigned u = __float_as_uint(f);
  return (short)((u + 0x7FFFu + ((u >> 16) & 1u)) >> 16);  // RNE
}
__device__ __forceinline__ float bf2f(short s) {
  return __uint_as_float(((unsigned)(unsigned short)s) << 16);
}
__device__ __forceinline__ unsigned pk2bf(float lo, float hi) {
  __hip_bfloat162 h = __float22bfloat162_rn(float2{lo, hi});  // v_cvt_pk_bf16_f32
  return *reinterpret_cast<unsigned*>(&h);
}
// packed gelu: x - x/(1+E), E = 2^(x*(a + a*0.044715*x^2)).
__device__ __forceinline__ f2 gelu2(f2 x) {
  f2 t = x * x;
  f2 z = x * (t * 0.10294322f + 2.3022077f);
  f2 e;
  e.x = __builtin_exp2f(z.x);
  e.y = __builtin_exp2f(z.y);
  f2 d = e + 1.0f;
  f2 r;
  r.x = __builtin_amdgcn_rcpf(d.x);
  r.y = __builtin_amdgcn_rcpf(d.y);
  return x - x * r;
}
__device__ __forceinline__ float gelu_old(float x) {
  float z = 0.7978845608028654f * fmaf(0.044715f * x, x * x, x);
  float e = __expf(2.0f * z);
  return 0.5f * x * (2.0f - 2.0f / (e + 1.0f));
}

// =================== fast path ===================

// aux2: [0,512) GF 64-pt units; [512,576) vq 64-latent units; [576,896) transposes.
__global__ __launch_bounds__(256, 3) void gno_aux2(
    const float* __restrict__ x, const float* __restrict__ gc,
    const float* __restrict__ latg, const float* __restrict__ W0,
    const float* __restrict__ b0,
    const float* __restrict__ W1, const float* __restrict__ W2,
    const float* __restrict__ W3,
    short* __restrict__ W1T, short* __restrict__ W2T, short* __restrict__ W3T,
    short* __restrict__ GF, float* __restrict__ vqPre) {
  __shared__ __align__(16) short w0S[128 * 104];   // 26624 B
  __shared__ __align__(16) short embS[64 * 104];   // 13312 B
  __shared__ float tableS[32][32];                 // [coord-idx][16 sin | 16 cos]
  __shared__ float valsS[32];
  __shared__ float xS[8][64];                      // (GF only)
  __shared__ float wfS[4][128];                    // (GF only)

  const int tid = threadIdx.x;
  const int u = blockIdx.x;

  if (u >= 576) {  // ---- weight transposes: 81920 elems over 320 blocks ----
    int g = (u - 576) * 256 + tid;
    if (g < 32768) {            // W1T [n=256][k=128]
      int nn = g >> 7, k = g & 127;
      W1T[g] = f2bf(W1[k * 256 + nn]);
    } else if (g < 65536) {     // W2T [n=128][k=256]
      int h = g - 32768, nn = h >> 8, k = h & 255;
      W2T[h] = f2bf(W2[k * 128 + nn]);
    } else {                    // W3T [n=128][k=128]
      int h = g - 65536, nn = h >> 7, k = h & 127;
      W3T[h] = f2bf(W3[k * 128 + nn]);
    }
    return;
  }

  const bool isGF = u < 512;
  const int p0 = isGF ? u * 64 : (u - 512) * 64;
  const int kbase = isGF ? 0 : 96;
  const int nvals = isGF ? 32 : 16;

  // stage W0 slice -> w0S bf16 [f(128)][k pad 104]
  for (int e = tid; e < 12288; e += 256) {
    int k = e >> 7, f = e & 127;
    w0S[f * 104 + k] = f2bf(W0[kbase * 128 + e]);
  }
  // axis coordinate values (all 3 axes share the same linspace)
  if (tid < nvals) valsS[tid] = isGF ? gc[tid * 3 + 2] : latg[tid * 3 + 2];
  if (isGF) {
#pragma unroll
    for (int uu = 0; uu < 2; ++uu) {
      int slot = tid * 2 + uu;  // 512 slots
      int bb = slot >> 8, ch = (slot >> 6) & 3, i = slot & 63;
      int n = p0 + i;
      xS[bb * 4 + ch][i] = x[((bb * 4 + ch) << 15) + ((n & 31) << 10) + (n >> 5)];
      wfS[slot >> 7][slot & 127] = W0[(192 + (slot >> 7)) * 128 + (slot & 127)];
    }
  }
  __syncthreads();
  {  // trig table: nvals x 32 entries
    for (int t = tid; t < nvals * 32; t += 256) {
      int vi = t >> 5, jj = t & 31;
      float fr = (float)exp(-(double)(jj & 15) * (9.210340371976184 / 16.0));
      float ca = valsS[vi];
      tableS[vi][jj] = (jj < 16) ? __sinf(ca * fr) : __cosf(ca * fr);
    }
  }
  __syncthreads();
  {  // embS by table lookup: 64 rows x 96 cols
    int rr = tid >> 2, c4 = tid & 3;
    int m = p0 + rr;
    int i0, i1, i2;
    if (isGF) { i0 = m >> 10; i1 = (m >> 5) & 31; i2 = m & 31; }
    else      { i0 = (m >> 8) & 15; i1 = (m >> 4) & 15; i2 = m & 15; }
    const int ia[3] = {i0, i1, i2};
#pragma unroll
    for (int c = c4 * 24; c < c4 * 24 + 24; ++c) {
      int a = c >> 5, jj = c & 31;
      embS[rr * 104 + c] = f2bf(tableS[ia[a]][jj]);
    }
  }
  __syncthreads();
  const int wid = tid >> 6, lane = tid & 63;
  const int l15 = lane & 15, lg = lane >> 4;
  const int f0 = wid * 32;
  f4 acc[2][4] = {};  // [ftile][ptile]; C: col=point(l15), row=feat(lg*4+i)
#pragma unroll
  for (int ks = 0; ks < 3; ++ks) {
    bs8 Aw[2], Be[4];
#pragma unroll
    for (int ft = 0; ft < 2; ++ft)
      Aw[ft] = *(const bs8*)(w0S + (f0 + ft * 16 + l15) * 104 + ks * 32 + lg * 8);
#pragma unroll
    for (int pt = 0; pt < 4; ++pt)
      Be[pt] = *(const bs8*)(embS + (pt * 16 + l15) * 104 + ks * 32 + lg * 8);
#pragma unroll
    for (int ft = 0; ft < 2; ++ft)
#pragma unroll
      for (int pt = 0; pt < 4; ++pt)
        acc[ft][pt] = MFMA16(Aw[ft], Be[pt], acc[ft][pt], 0, 0, 0);
  }
  if (!isGF) {  // vq epilogue: vqPre[q][f] = acc + b0[f], f32
#pragma unroll
    for (int ft = 0; ft < 2; ++ft) {
      f4 bias = *(const f4*)(b0 + f0 + ft * 16 + lg * 4);
#pragma unroll
      for (int pt = 0; pt < 4; ++pt) {
        int q = p0 + pt * 16 + l15;
        *(f4*)(vqPre + q * 128 + f0 + ft * 16 + lg * 4) = acc[ft][pt] + bias;
      }
    }
    return;
  }
  // GF epilogue: + x@W0[192:196], pack bf16, direct uint2 stores (r3 pattern)
#pragma unroll
  for (int ft = 0; ft < 2; ++ft) {
    f4 wf0 = *(const f4*)(&wfS[0][f0 + ft * 16 + lg * 4]);
    f4 wf1 = *(const f4*)(&wfS[1][f0 + ft * 16 + lg * 4]);
    f4 wf2 = *(const f4*)(&wfS[2][f0 + ft * 16 + lg * 4]);
    f4 wf3 = *(const f4*)(&wfS[3][f0 + ft * 16 + lg * 4]);
#pragma unroll
    for (int pt = 0; pt < 4; ++pt) {
      int p = pt * 16 + l15;
#pragma unroll
      for (int bb = 0; bb < 2; ++bb) {
        float x0 = xS[bb * 4 + 0][p], x1 = xS[bb * 4 + 1][p];
        float x2 = xS[bb * 4 + 2][p], x3 = xS[bb * 4 + 3][p];
        float v0 = acc[ft][pt][0] + x0 * wf0[0] + x1 * wf1[0] + x2 * wf2[0] + x3 * wf3[0];
        float v1 = acc[ft][pt][1] + x0 * wf0[1] + x1 * wf1[1] + x2 * wf2[1] + x3 * wf3[1];
        float v2 = acc[ft][pt][2] + x0 * wf0[2] + x1 * wf1[2] + x2 * wf2[2] + x3 * wf3[2];
        float v3 = acc[ft][pt][3] + x0 * wf0[3] + x1 * wf1[3] + x2 * wf2[3] + x3 * wf3[3];
        uint2 pp;
        pp.x = pk2bf(v0, v1);
        pp.y = pk2bf(v2, v3);
        *(uint2*)(GF + ((size_t)((bb << 15) + p0 + p)) * 128 + f0 + ft * 16 + lg * 4) = pp;
      }
    }
  }
}

// h0: gelu(GF + vq) for 8 bf16 packed in a uint4, fully pk.
__device__ __forceinline__ uint4 gelu8u(uint4 gu, const float* vrow) {
  uint4 r;
  const unsigned ua[4] = {gu.x, gu.y, gu.z, gu.w};
  unsigned ro[4];
#pragma unroll
  for (int j = 0; j < 4; ++j) {
    f2 xx;
    xx.x = __uint_as_float(ua[j] << 16);
    xx.y = __uint_as_float(ua[j] & 0xFFFF0000u);
    xx += *(const f2*)(vrow + 2 * j);
    f2 g = gelu2(xx);
    ro[j] = pk2bf(g.x, g.y);
  }
  r.x = ro[0]; r.y = ro[1]; r.z = ro[2]; r.w = ro[3];
  return r;
}

// main7: block = (b, 4 q) = 128 rows; 8 waves (512 thr); h1 in 2x128-col chunks;
// fused W3 epilogue. 2048 blocks.
__global__ __launch_bounds__(512, 4) void gno_main7(
    const float* __restrict__ gc, const float* __restrict__ latg,
    const int* __restrict__ nidx,
    const float* __restrict__ b1, const float* __restrict__ b2,
    const float* __restrict__ b3,
    const short* __restrict__ W1T, const short* __restrict__ W2T,
    const short* __restrict__ W3T,
    const float* __restrict__ vqPre, const short* __restrict__ GF,
    float* __restrict__ out) {
  __shared__ __align__(16) short h0S[128][136];   // rows 0..3 reused as h2b
  __shared__ __align__(16) short h1S[128][136];   // one 128-col chunk of h1
  __shared__ float vqS[4][128];
  __shared__ float maskfS[128];
  __shared__ float b3S[128];
  __shared__ float cntS[4];

  const int tid = threadIdx.x;
  const int blk = blockIdx.x;
  const int b = blk >> 10;
  const int q0 = (blk & 1023) * 4;

  vqS[tid >> 7][tid & 127] = vqPre[(q0 + (tid >> 7)) * 128 + (tid & 127)];
  if (tid < 128) b3S[tid] = b3[tid];

  const int r = tid >> 2, seg = tid & 3;   // r: 0..127 rows, seg: 32-col segment
  const int qh = r >> 5;
  const int n = nidx[(q0 + qh) * 32 + (r & 31)];
  const uint4* gp = (const uint4*)(GF + ((size_t)((b << 15) + n)) * 128 + seg * 32);
  uint4 g0 = gp[0], g1 = gp[1], g2 = gp[2], g3 = gp[3];
  if (seg == 0) {  // exact mask (fp32 arith, double cmp — replicates setup bit-exactly)
    float la = latg[(q0 + qh) * 3], lb = latg[(q0 + qh) * 3 + 1], lc = latg[(q0 + qh) * 3 + 2];
    float d0 = __fsub_rn(la, gc[n * 3]);
    float d1 = __fsub_rn(lb, gc[n * 3 + 1]);
    float d2 = __fsub_rn(lc, gc[n * 3 + 2]);
    float s = __fadd_rn(__fadd_rn(__fmul_rn(d0, d0), __fmul_rn(d1, d1)), __fmul_rn(d2, d2));
    maskfS[r] = ((double)s <= 0.055 * 0.055) ? 1.0f : 0.0f;
  }
  __syncthreads();  // vqS ready
  {  // h0 = gelu(GF + vq)
    const float* vrow = vqS[qh] + seg * 32;
    *(uint4*)(&h0S[r][seg * 32]) = gelu8u(g0, vrow);
    *(uint4*)(&h0S[r][seg * 32 + 8]) = gelu8u(g1, vrow + 8);
    *(uint4*)(&h0S[r][seg * 32 + 16]) = gelu8u(g2, vrow + 16);
    *(uint4*)(&h0S[r][seg * 32 + 24]) = gelu8u(g3, vrow + 24);
  }
  __syncthreads();  // h0S + mask ready
  if (tid < 4) {  // neighbor count per q
    float s = 0.0f;
#pragma unroll
    for (int i = 0; i < 32; ++i) s += maskfS[tid * 32 + i];
    cntS[tid] = s;
  }

  const int wid = tid >> 6, lane = tid & 63;
  const int l15 = lane & 15, lg = lane >> 4;
  const int mh = wid >> 1, nh = wid & 1;  // L2 roles: mh = q-row-group, nh = feat-half
  f4 accL2[4][2] = {};                    // persists across chunks

#pragma unroll 1
  for (int c = 0; c < 2; ++c) {
    {  // L1 chunk: wave owns 16 feats x all 128 rows
      const int fg = c * 128 + wid * 16;  // global h1 feature base
      f4 acc1[8] = {};
#pragma unroll
      for (int ks = 0; ks < 4; ++ks) {
        bs8 Aw = *(const bs8*)(W1T + (fg + l15) * 128 + ks * 32 + lg * 8);
#pragma unroll
        for (int rt = 0; rt < 8; ++rt) {
          bs8 Bh = *(const bs8*)(&h0S[rt * 16 + l15][ks * 32 + lg * 8]);
          acc1[rt] = MFMA16(Aw, Bh, acc1[rt], 0, 0, 0);
        }
      }
      f4 bias = *(const f4*)(b1 + fg + lg * 4);
#pragma unroll
      for (int rt = 0; rt < 8; ++rt) {
        f2 a = {acc1[rt][0] + bias[0], acc1[rt][1] + bias[1]};
        f2 bp = {acc1[rt][2] + bias[2], acc1[rt][3] + bias[3]};
        f2 ga = gelu2(a);
        f2 gb = gelu2(bp);
        uint2 p;
        p.x = pk2bf(ga.x, ga.y);
        p.y = pk2bf(gb.x, gb.y);
        *(uint2*)(&h1S[rt * 16 + l15][wid * 16 + lg * 4]) = p;
      }
    }
    __syncthreads();  // h1 chunk ready
    {  // L2 partial-K: wave (mh: rows of q0+mh) x (nh: 64 out-feats)
      const int fo = nh * 64;
#pragma unroll
      for (int ks = 0; ks < 4; ++ks) {
        bs8 Ah[2], Bw[4];
#pragma unroll
        for (int rt = 0; rt < 2; ++rt)
          Ah[rt] = *(const bs8*)(&h1S[mh * 32 + rt * 16 + l15][ks * 32 + lg * 8]);
#pragma unroll
        for (int ct = 0; ct < 4; ++ct)
          Bw[ct] = *(const bs8*)(W2T + (fo + ct * 16 + l15) * 256 + c * 128 + ks * 32 + lg * 8);
#pragma unroll
        for (int ct = 0; ct < 4; ++ct)
#pragma unroll
          for (int rt = 0; rt < 2; ++rt)
            accL2[ct][rt] = MFMA16(Ah[rt], Bw[ct], accL2[ct][rt], 0, 0, 0);
      }
    }
    __syncthreads();  // done reading h1 chunk before overwrite
  }

  {  // L2 epilogue: pk gelu + mask + per-q row-sum -> h2b (h0S rows 0..3) bf16
    const int fo = nh * 64;
    float psum[4];
#pragma unroll
    for (int ct = 0; ct < 4; ++ct) {
      float bias = b2[fo + ct * 16 + l15];
      float s = 0.0f;
#pragma unroll
      for (int rt = 0; rt < 2; ++rt) {
        f2 u0 = {accL2[ct][rt][0] + bias, accL2[ct][rt][1] + bias};
        f2 u1 = {accL2[ct][rt][2] + bias, accL2[ct][rt][3] + bias};
        f2 gA = gelu2(u0);
        f2 gB = gelu2(u1);
        int row = mh * 32 + rt * 16 + lg * 4;
        s += gA.x * maskfS[row] + gA.y * maskfS[row + 1] +
             gB.x * maskfS[row + 2] + gB.y * maskfS[row + 3];
      }
      psum[ct] = s;
    }
#pragma unroll
    for (int ct = 0; ct < 4; ++ct) {
      psum[ct] += __shfl_xor(psum[ct], 16, 64);
      psum[ct] += __shfl_xor(psum[ct], 32, 64);
    }
    if (lane < 16) {
#pragma unroll
      for (int ct = 0; ct < 4; ++ct)
        h0S[mh][fo + ct * 16 + lane] = f2bf(psum[ct]);
    }
  }
  __syncthreads();  // h2b ready (rows 0..3; rows 4..15 stale h0 = finite)
  {  // fused W3: out = h2b @ W3 + cnt*b3, direct transposed store
    const int wf = wid * 16;
    f4 a3 = {};  // C: col(l15)=feat-within-16? no: col=B-col=feat, row=q-row
#pragma unroll
    for (int ks = 0; ks < 4; ++ks) {
      bs8 Ah = *(const bs8*)(&h0S[l15][ks * 32 + lg * 8]);
      bs8 Bw = *(const bs8*)(W3T + (wf + l15) * 128 + ks * 32 + lg * 8);
      a3 = MFMA16(Ah, Bw, a3, 0, 0, 0);
    }
    if (lg == 0) {
      int feat = wf + l15;
      float bb3 = b3S[feat];
#pragma unroll
      for (int i = 0; i < 4; ++i) {
        int q = q0 + i;
        out[(b << 19) + (feat << 12) + ((q & 15) << 8) + ((q >> 8) << 4) +
            ((q >> 4) & 15)] = a3[i] + cntS[i] * bb3;
      }
    }
  }
}

// =================== old (fallback) path — round-1 kernels ===================

__global__ void gno_prep(const float* __restrict__ W0, const float* __restrict__ W1,
                         const float* __restrict__ W2, const float* __restrict__ W3,
                         short* __restrict__ W0aT, short* __restrict__ W1T,
                         short* __restrict__ W2T, short* __restrict__ W3T) {
  int g = blockIdx.x * 256 + threadIdx.x;
  if (g < 16384) {
    int n = g >> 7, k = g & 127;
    float v = (k < 96) ? W0[k * 128 + n] : ((k < 100) ? W0[(k + 96) * 128 + n] : 0.0f);
    W0aT[g] = f2bf(v);
  } else if (g < 49152) {
    int h = g - 16384, n = h >> 7, k = h & 127;
    W1T[h] = f2bf(W1[k * 256 + n]);
  } else if (g < 81920) {
    int h = g - 49152, n = h >> 8, k = h & 255;
    W2T[h] = f2bf(W2[k * 128 + n]);
  } else if (g < 98304) {
    int h = g - 81920, n = h >> 7, k = h & 127;
    W3T[h] = f2bf(W3[k * 128 + n]);
  }
}

template <int SIN, int K>
__device__ __forceinline__ void gemm_block(const short* inS, const short* __restrict__ WT,
                                           int colBase, int lane, f4 (&acc)[2][4]) {
  constexpr int KS = K / 32;
  bs8 Bf[2][KS];
  const int bcol = lane & 15;
  const int bk = (lane >> 4) * 8;
#pragma unroll
  for (int ct = 0; ct < 2; ++ct)
#pragma unroll
    for (int ks = 0; ks < KS; ++ks)
      Bf[ct][ks] = *reinterpret_cast<const bs8*>(WT + (colBase + ct * 16 + bcol) * K + ks * 32 + bk);
#pragma unroll
  for (int mt = 0; mt < 4; ++mt) {
#pragma unroll
    for (int ks = 0; ks < KS; ++ks) {
      bs8 Af = *reinterpret_cast<const bs8*>(inS + (mt * 16 + bcol) * SIN + ks * 32 + bk);
      acc[0][mt] = MFMA16(Af, Bf[0][ks], acc[0][mt], 0, 0, 0);
      acc[1][mt] = MFMA16(Af, Bf[1][ks], acc[1][mt], 0, 0, 0);
    }
  }
}

__global__ __launch_bounds__(256, 2) void gno_main(
    const float* __restrict__ x, const float* __restrict__ gc,
    const float* __restrict__ latg, const int* __restrict__ nidx,
    const float* __restrict__ W0, const float* __restrict__ b0,
    const float* __restrict__ b1, const float* __restrict__ b2,
    const float* __restrict__ b3,
    const short* __restrict__ W0aT, const short* __restrict__ W1T,
    const short* __restrict__ W2T, const short* __restrict__ W3T,
    float* __restrict__ dst, int direct) {
  __shared__ __align__(16) short aggS[64][136];
  __shared__ __align__(16) short h0S[64][136];
  __shared__ __align__(16) short h1S[64][264];
  __shared__ float vqS[2][128];
  __shared__ float maskfS[64];
  __shared__ float freqS[16];
  __shared__ float latS[2][3];
  __shared__ float sEmbQ[2][96];

  const int tid = threadIdx.x;
  const int blk = blockIdx.x;
  const int b = blk >> 11;
  const int q0 = (blk & 2047) * 2;

  if (tid < 16) freqS[tid] = (float)exp(-(double)tid * (9.210340371976184 / 16.0));
  if (tid >= 32 && tid < 38) {
    int t = tid - 32, qh = t / 3, a = t % 3;
    latS[qh][a] = latg[(q0 + qh) * 3 + a];
  }
  __syncthreads();
  if (tid < 192) {
    int qh = tid / 96, c = tid % 96, a = c >> 5, jj = c & 31;
    float ca = latS[qh][a];
    sEmbQ[qh][c] = (jj < 16) ? __sinf(ca * freqS[jj]) : __cosf(ca * freqS[jj & 15]);
  }
  __syncthreads();
  {
    int qh = tid >> 7, o = tid & 127;
    float s = b0[o];
#pragma unroll 4
    for (int j = 0; j < 96; ++j) s = fmaf(sEmbQ[qh][j], W0[(96 + j) * 128 + o], s);
    vqS[qh][o] = s;
  }
  {
    int r = tid >> 2, qq = tid & 3;
    int qh = r >> 5, kk = r & 31;
    int n = nidx[(q0 + qh) * 32 + kk];
    float c0 = gc[n * 3], c1 = gc[n * 3 + 1], c2 = gc[n * 3 + 2];
    if (qq == 0) {
      float d0 = __fsub_rn(latS[qh][0], c0);
      float d1 = __fsub_rn(latS[qh][1], c1);
      float d2 = __fsub_rn(latS[qh][2], c2);
      float s = __fadd_rn(__fadd_rn(__fmul_rn(d0, d0), __fmul_rn(d1, d1)), __fmul_rn(d2, d2));
      maskfS[r] = ((double)s <= 0.055 * 0.055) ? 1.0f : 0.0f;
    }
    float cc[3] = {c0, c1, c2};
    for (int c = qq * 34; c < qq * 34 + 34; ++c) {
      float v = 0.0f;
      if (c < 96) {
        int a = c >> 5, jj = c & 31;
        v = (jj < 16) ? __sinf(cc[a] * freqS[jj]) : __cosf(cc[a] * freqS[jj & 15]);
      } else if (c < 100) {
        int ch = c - 96;
        v = x[((b * 4 + ch) << 15) + ((n & 31) << 10) + (n >> 5)];
      }
      aggS[r][c] = f2bf(v);
    }
  }
  __syncthreads();

  const int wave = tid >> 6, lane = tid & 63;
  const int colBase = wave * 32;
  const int lrow4 = (lane >> 4) << 2;
  const int lcol = lane & 15;

  {
    f4 acc[2][4] = {};
    gemm_block<136, 128>(&aggS[0][0], W0aT, colBase, lane, acc);
#pragma unroll
    for (int ct = 0; ct < 2; ++ct) {
      int gcol = colBase + ct * 16 + lcol;
#pragma unroll
      for (int mt = 0; mt < 4; ++mt)
#pragma unroll
        for (int i = 0; i < 4; ++i) {
          int grow = mt * 16 + lrow4 + i;
          h0S[grow][gcol] = f2bf(gelu_old(acc[ct][mt][i] + vqS[grow >> 5][gcol]));
        }
    }
  }
  __syncthreads();
  {
#pragma unroll 1
    for (int cg = 0; cg < 2; ++cg) {
      int cb = wave * 64 + cg * 32;
      f4 acc[2][4] = {};
      gemm_block<136, 128>(&h0S[0][0], W1T, cb, lane, acc);
#pragma unroll
      for (int ct = 0; ct < 2; ++ct) {
        int gcol = cb + ct * 16 + lcol;
        float bias = b1[gcol];
#pragma unroll
        for (int mt = 0; mt < 4; ++mt)
#pragma unroll
          for (int i = 0; i < 4; ++i) {
            int grow = mt * 16 + lrow4 + i;
            h1S[grow][gcol] = f2bf(gelu_old(acc[ct][mt][i] + bias));
          }
      }
    }
  }
  __syncthreads();
  {
    f4 acc[2][4] = {};
    gemm_block<264, 256>(&h1S[0][0], W2T, colBase, lane, acc);
#pragma unroll
    for (int ct = 0; ct < 2; ++ct) {
      int gcol = colBase + ct * 16 + lcol;
      float bias = b2[gcol];
#pragma unroll
      for (int mt = 0; mt < 4; ++mt)
#pragma unroll
        for (int i = 0; i < 4; ++i) {
          int grow = mt * 16 + lrow4 + i;
          aggS[grow][gcol] = f2bf(gelu_old(acc[ct][mt][i] + bias));
        }
    }
  }
  __syncthreads();
  {
    f4 acc[2][4] = {};
    gemm_block<136, 128>(&aggS[0][0], W3T, colBase, lane, acc);
    float part[2][2] = {{0.0f, 0.0f}, {0.0f, 0.0f}};
#pragma unroll
    for (int ct = 0; ct < 2; ++ct) {
      float bias = b3[colBase + ct * 16 + lcol];
#pragma unroll
      for (int mt = 0; mt < 4; ++mt)
#pragma unroll
        for (int i = 0; i < 4; ++i) {
          int grow = mt * 16 + lrow4 + i;
          part[mt >> 1][ct] += (acc[ct][mt][i] + bias) * maskfS[grow];
        }
    }
#pragma unroll
    for (int qh = 0; qh < 2; ++qh)
#pragma unroll
      for (int ct = 0; ct < 2; ++ct) {
        float v = part[qh][ct];
        v += __shfl_xor(v, 16, 64);
        v += __shfl_xor(v, 32, 64);
        if (lane < 16) {
          int o = colBase + ct * 16 + lane;
          int q = q0 + qh;
          if (direct)
            dst[(b << 19) + (o << 12) + ((q & 15) << 8) + ((q >> 8) << 4) + ((q >> 4) & 15)] = v;
          else
            dst[(b * 4096 + q) * 128 + o] = v;
        }
      }
  }
}

__global__ void gno_tr(const float* __restrict__ staged, float* __restrict__ out) {
  __shared__ float tile[16][129];
  int blk = blockIdx.x;
  int b = blk >> 8, i = (blk >> 4) & 15, l = blk & 15;
  int t = threadIdx.x;
  {
    int j = t >> 4, oc = t & 15;
    const float* src = staged + ((b * 4096) + (i * 256 + j * 16 + l)) * 128 + oc * 8;
#pragma unroll
    for (int u = 0; u < 8; ++u) tile[j][oc * 8 + u] = src[u];
  }
  __syncthreads();
  {
    int og = t >> 4, j = t & 15;
#pragma unroll
    for (int oo = 0; oo < 8; ++oo) {
      int o = og * 8 + oo;
      out[(b << 19) + (o << 12) + (l << 8) + (i << 4) + j] = tile[j][o];
    }
  }
}

extern "C" void kernel_launch(void* const* d_in, const int* in_sizes, int n_in,
                              void* d_out, int out_size, void* d_ws, size_t ws_size,
                              hipStream_t stream) {
  const float* x    = (const float*)d_in[0];
  const float* gc   = (const float*)d_in[1];
  const float* latg = (const float*)d_in[2];
  const int*   nidx = (const int*)d_in[3];
  const float* W0 = (const float*)d_in[5];
  const float* b0 = (const float*)d_in[6];
  const float* W1 = (const float*)d_in[7];
  const float* b1 = (const float*)d_in[8];
  const float* W2 = (const float*)d_in[9];
  const float* b2 = (const float*)d_in[10];
  const float* W3 = (const float*)d_in[11];
  const float* b3 = (const float*)d_in[12];

  char* ws = (char*)d_ws;
  float* out = (float*)d_out;

  if (ws_size >= (size_t)FAST_NEED) {
    short* W1T  = (short*)(ws + W1T_OFF);
    short* W2T  = (short*)(ws + W2T_OFF);
    short* W3T  = (short*)(ws + W3T_OFF);
    float* vqPre = (float*)(ws + VQ_OFF);
    short* GF = (short*)(ws + GF_OFF);
    gno_aux2<<<896, 256, 0, stream>>>(x, gc, latg, W0, b0, W1, W2, W3,
                                      W1T, W2T, W3T, GF, vqPre);
    gno_main7<<<2048, 512, 0, stream>>>(gc, latg, nidx, b1, b2, b3,
                                        W1T, W2T, W3T, vqPre, GF, out);
  } else {
    short* W0aT = (short*)(ws + OW0AT_OFF);
    short* W1T  = (short*)(ws + OW1T_OFF);
    short* W2T  = (short*)(ws + OW2T_OFF);
    short* W3T  = (short*)(ws + OW3T_OFF);
    float* staged = (float*)(ws + OSTAGED_OFF);
    const bool use_staged = (ws_size >= (size_t)OLD_NEED);
    gno_prep<<<384, 256, 0, stream>>>(W0, W1, W2, W3, W0aT, W1T, W2T, W3T);
    gno_main<<<4096, 256, 0, stream>>>(x, gc, latg, nidx, W0, b0, b1, b2, b3,
                                       W0aT, W1T, W2T, W3T,
                                       use_staged ? staged : out, use_staged ? 0 : 1);
    if (use_staged) gno_tr<<<512, 256, 0, stream>>>(staged, out);
  }
}

// Round 9
// 210.940 us; speedup vs baseline: 1.3488x; 1.0440x over previous
//
#include <hip/hip_runtime.h>
#include <hip/hip_bf16.h>
#include <math.h>

// GNO stem, round 9: eliminate GF precompute (aux was ~60us: per-block W0 LDS
// re-staging + scattered stores + 17MB GF round-trip). L0 now inlined in main:
//  - 48x32 bf16 trig table (grid/lat axes are shared linspaces) rebuilds all
//    embeddings AND bit-exact mask coords by index math -> no gc/latg gathers.
//  - L0 = per-wave K=96 GEMM vs W0eT frags (L2-resident); 4 latent rows ride as
//    B-tile row 8 vs W0mT -> vq in-block (only l15<4 cols of that tile are read;
//    MFMA cols are independent so garbage rows are safe).
//  - x contribution + vq add in f32 epilogue (unchanged numerics).
//  - 2 launches: prep4 (pure weight transpose, 416 blk) -> main8 (2048 x 512).

typedef short bs8 __attribute__((ext_vector_type(8)));
typedef float f4  __attribute__((ext_vector_type(4)));
typedef float f2  __attribute__((ext_vector_type(2)));

#define MFMA16 __builtin_amdgcn_mfma_f32_16x16x32_bf16

// ---------- fast-path ws layout (bytes) ----------
#define W1T_OFF    0u          // [256][128] bf16  65536
#define W2T_OFF    65536u      // [128][256] bf16  65536
#define W3T_OFF    131072u     // [128][128] bf16  32768
#define W0ET_OFF   163840u     // [128][96]  bf16  24576
#define W0MT_OFF   188416u     // [128][96]  bf16  24576
#define FAST_NEED  212992u

// ---------- old-path ws layout ----------
#define OW0AT_OFF   0
#define OW1T_OFF    32768
#define OW2T_OFF    98304
#define OW3T_OFF    163840
#define OSTAGED_OFF 196608
#define OLD_NEED    (196608 + 4194304)

__device__ __forceinline__ short f2bf(float f) {
  unsigned u = __float_as_uint(f);
  return (short)((u + 0x7FFFu + ((u >> 16) & 1u)) >> 16);  // RNE
}
__device__ __forceinline__ float bf2f(short s) {
  return __uint_as_float(((unsigned)(unsigned short)s) << 16);
}
__device__ __forceinline__ unsigned pk2bf(float lo, float hi) {
  __hip_bfloat162 h = __float22bfloat162_rn(float2{lo, hi});  // v_cvt_pk_bf16_f32
  return *reinterpret_cast<unsigned*>(&h);
}
// packed gelu: x - x/(1+E), E = 2^(x*(a + a*0.044715*x^2)).
__device__ __forceinline__ f2 gelu2(f2 x) {
  f2 t = x * x;
  f2 z = x * (t * 0.10294322f + 2.3022077f);
  f2 e;
  e.x = __builtin_exp2f(z.x);
  e.y = __builtin_exp2f(z.y);
  f2 d = e + 1.0f;
  f2 r;
  r.x = __builtin_amdgcn_rcpf(d.x);
  r.y = __builtin_amdgcn_rcpf(d.y);
  return x - x * r;
}
__device__ __forceinline__ float gelu_old(float x) {
  float z = 0.7978845608028654f * fmaf(0.044715f * x, x * x, x);
  float e = __expf(2.0f * z);
  return 0.5f * x * (2.0f - 2.0f / (e + 1.0f));
}

// =================== fast path ===================

// prep4: all weight transposes. 106496 elems, 416 blocks.
__global__ void gno_prep4(const float* __restrict__ W0, const float* __restrict__ W1,
                          const float* __restrict__ W2, const float* __restrict__ W3,
                          short* __restrict__ W1T, short* __restrict__ W2T,
                          short* __restrict__ W3T, short* __restrict__ W0eT,
                          short* __restrict__ W0mT) {
  int g = blockIdx.x * 256 + threadIdx.x;
  if (g < 32768) {                 // W1T [256][128]
    int nn = g >> 7, k = g & 127;
    W1T[g] = f2bf(W1[k * 256 + nn]);
  } else if (g < 65536) {          // W2T [128][256]
    int h = g - 32768, nn = h >> 8, k = h & 255;
    W2T[h] = f2bf(W2[k * 128 + nn]);
  } else if (g < 81920) {          // W3T [128][128]
    int h = g - 65536, nn = h >> 7, k = h & 127;
    W3T[h] = f2bf(W3[k * 128 + nn]);
  } else if (g < 94208) {          // W0eT [128][96]
    int h = g - 81920, nn = h / 96, k = h % 96;
    W0eT[h] = f2bf(W0[k * 128 + nn]);
  } else if (g < 106496) {         // W0mT [128][96]
    int h = g - 94208, nn = h / 96, k = h % 96;
    W0mT[h] = f2bf(W0[(96 + k) * 128 + nn]);
  }
}

// main8: block = (b, 4 q) = 128 rows; 8 waves (512 thr); inline L0+vq; h1 in
// 2x128-col chunks; fused W3 epilogue. 2048 blocks.
__global__ __launch_bounds__(512, 4) void gno_main8(
    const int* __restrict__ nidx, const float* __restrict__ x,
    const float* __restrict__ gc, const float* __restrict__ latg,
    const float* __restrict__ W0, const float* __restrict__ b0,
    const float* __restrict__ b1, const float* __restrict__ b2,
    const float* __restrict__ b3,
    const short* __restrict__ W0eT, const short* __restrict__ W0mT,
    const short* __restrict__ W1T, const short* __restrict__ W2T,
    const short* __restrict__ W3T,
    float* __restrict__ out) {
  __shared__ __align__(16) short h0S[128][136];   // rows 0..3 reused as h2b
  __shared__ __align__(16) short h1S[128][136];   // embS alias first, then h1 chunk
  __shared__ __align__(16) short tabBS[48][32];   // bf16 trig: rows 0-31 gc, 32-47 lat
  __shared__ float vals32S[32];
  __shared__ float vals16S[16];
  __shared__ float xS[4][128];
  __shared__ float vqS[4][128];
  __shared__ float maskfS[128];
  __shared__ float b3S[128];
  __shared__ float cntS[4];

  const int tid = threadIdx.x;
  const int blk = blockIdx.x;
  const int b = blk >> 10;
  const int q0 = (blk & 1023) * 4;
  short* embS = &h1S[0][0];  // [132][104] (<= h1S extent)

  // P0: axis values + b3
  if (tid < 32) vals32S[tid] = gc[tid * 3 + 2];         // td == th == tw (linspace)
  else if (tid < 48) vals16S[tid - 32] = latg[(tid - 32) * 3 + 2];
  if (tid < 128) b3S[tid] = b3[tid];
  __syncthreads();

  const int r = tid >> 2, c4 = tid & 3;     // 4 threads per row
  const int qh = r >> 5;
  const int n = nidx[(q0 + qh) * 32 + (r & 31)];

  // P1: trig table + x gather + exact mask
  for (int t = tid; t < 1536; t += 512) {
    int vi = t >> 5, jj = t & 31;
    float ca = (vi < 32) ? vals32S[vi] : vals16S[vi - 32];
    float fr = (float)exp(-(double)(jj & 15) * (9.210340371976184 / 16.0));
    tabBS[vi][jj] = f2bf((jj < 16) ? __sinf(ca * fr) : __cosf(ca * fr));
  }
  xS[c4][r] = x[((b * 4 + c4) << 15) + ((n & 31) << 10) + (n >> 5)];
  if (c4 == 0) {  // mask from table values (bit-exact: same linspace floats)
    int q = q0 + qh;
    float d0 = __fsub_rn(vals16S[q >> 8], vals32S[n >> 10]);
    float d1 = __fsub_rn(vals16S[(q >> 4) & 15], vals32S[(n >> 5) & 31]);
    float d2 = __fsub_rn(vals16S[q & 15], vals32S[n & 31]);
    float s = __fadd_rn(__fadd_rn(__fmul_rn(d0, d0), __fmul_rn(d1, d1)), __fmul_rn(d2, d2));
    maskfS[r] = ((double)s <= 0.055 * 0.055) ? 1.0f : 0.0f;
  }
  __syncthreads();

  // P2: emb assembly (neighbor rows 0..127; latent rows 128..131) + cnt
  {
    const int ia[3] = {n >> 10, (n >> 5) & 31, n & 31};
#pragma unroll
    for (int cc = 0; cc < 12; ++cc) {
      int c = c4 * 24 + cc * 2;
      int a = c >> 5;
      unsigned lo = (unsigned short)tabBS[ia[a]][c & 31];
      unsigned hi = (unsigned short)tabBS[ia[a]][(c & 31) + 1];
      *(unsigned*)(embS + r * 104 + c) = lo | (hi << 16);
    }
    if (tid < 16) {  // latent row 128+r (r<4), q = q0+r
      int q = q0 + r;
      const int la[3] = {32 + (q >> 8), 32 + ((q >> 4) & 15), 32 + (q & 15)};
#pragma unroll
      for (int cc = 0; cc < 12; ++cc) {
        int c = c4 * 24 + cc * 2;
        int a = c >> 5;
        unsigned lo = (unsigned short)tabBS[la[a]][c & 31];
        unsigned hi = (unsigned short)tabBS[la[a]][(c & 31) + 1];
        *(unsigned*)(embS + (128 + r) * 104 + c) = lo | (hi << 16);
      }
    }
  }
  if (tid >= 32 && tid < 36) {  // cnt per q
    float s = 0.0f;
#pragma unroll
    for (int i = 0; i < 32; ++i) s += maskfS[(tid - 32) * 32 + i];
    cntS[tid - 32] = s;
  }
  __syncthreads();

  const int wid = tid >> 6, lane = tid & 63;
  const int l15 = lane & 15, lg = lane >> 4;
  const int fg0 = wid * 16;  // this wave's 16 h0-features

  // P3: L0 GEMM (K=96) + vq rows
  f4 acc1[8] = {};
  f4 accv = {};
#pragma unroll
  for (int ks = 0; ks < 3; ++ks) {
    bs8 Aw = *(const bs8*)(W0eT + (fg0 + l15) * 96 + ks * 32 + lg * 8);
#pragma unroll
    for (int rt = 0; rt < 8; ++rt) {
      bs8 Bh = *(const bs8*)(embS + (rt * 16 + l15) * 104 + ks * 32 + lg * 8);
      acc1[rt] = MFMA16(Aw, Bh, acc1[rt], 0, 0, 0);
    }
    bs8 Awm = *(const bs8*)(W0mT + (fg0 + l15) * 96 + ks * 32 + lg * 8);
    bs8 Bl = *(const bs8*)(embS + (128 + l15) * 104 + ks * 32 + lg * 8);
    accv = MFMA16(Awm, Bl, accv, 0, 0, 0);
  }
  if (l15 < 4) {  // vq[q][f] = acc + b0[f]
    f4 bias0 = *(const f4*)(b0 + fg0 + lg * 4);
    *(f4*)(&vqS[l15][fg0 + lg * 4]) = accv + bias0;
  }
  __syncthreads();  // vqS ready; all embS reads done

  // P4: h0 = gelu(L0 + vq + x@wf) -> h0S
  {
    f4 wf0 = *(const f4*)(W0 + 192 * 128 + fg0 + lg * 4);
    f4 wf1 = *(const f4*)(W0 + 193 * 128 + fg0 + lg * 4);
    f4 wf2 = *(const f4*)(W0 + 194 * 128 + fg0 + lg * 4);
    f4 wf3 = *(const f4*)(W0 + 195 * 128 + fg0 + lg * 4);
#pragma unroll
    for (int rt = 0; rt < 8; ++rt) {
      int row = rt * 16 + l15;
      f4 vq = *(const f4*)(&vqS[rt >> 1][fg0 + lg * 4]);
      float x0 = xS[0][row], x1 = xS[1][row], x2 = xS[2][row], x3 = xS[3][row];
      f4 v;
#pragma unroll
      for (int i = 0; i < 4; ++i)
        v[i] = acc1[rt][i] + vq[i] + x0 * wf0[i] + x1 * wf1[i] + x2 * wf2[i] + x3 * wf3[i];
      f2 ga = gelu2(f2{v[0], v[1]});
      f2 gb = gelu2(f2{v[2], v[3]});
      uint2 p;
      p.x = pk2bf(ga.x, ga.y);
      p.y = pk2bf(gb.x, gb.y);
      *(uint2*)(&h0S[row][fg0 + lg * 4]) = p;
    }
  }
  __syncthreads();  // h0S ready; embS (h1S) free

  const int mh = wid >> 1, nh = wid & 1;  // L2 roles
  f4 accL2[4][2] = {};

#pragma unroll 1
  for (int c = 0; c < 2; ++c) {
    {  // L1 chunk: wave owns 16 feats x all 128 rows
      const int fg = c * 128 + wid * 16;
      f4 a1[8] = {};
#pragma unroll
      for (int ks = 0; ks < 4; ++ks) {
        bs8 Aw = *(const bs8*)(W1T + (fg + l15) * 128 + ks * 32 + lg * 8);
#pragma unroll
        for (int rt = 0; rt < 8; ++rt) {
          bs8 Bh = *(const bs8*)(&h0S[rt * 16 + l15][ks * 32 + lg * 8]);
          a1[rt] = MFMA16(Aw, Bh, a1[rt], 0, 0, 0);
        }
      }
      f4 bias = *(const f4*)(b1 + fg + lg * 4);
#pragma unroll
      for (int rt = 0; rt < 8; ++rt) {
        f2 a = {a1[rt][0] + bias[0], a1[rt][1] + bias[1]};
        f2 bp = {a1[rt][2] + bias[2], a1[rt][3] + bias[3]};
        f2 ga = gelu2(a);
        f2 gb = gelu2(bp);
        uint2 p;
        p.x = pk2bf(ga.x, ga.y);
        p.y = pk2bf(gb.x, gb.y);
        *(uint2*)(&h1S[rt * 16 + l15][wid * 16 + lg * 4]) = p;
      }
    }
    __syncthreads();  // h1 chunk ready
    {  // L2 partial-K: wave (mh: rows of q0+mh) x (nh: 64 out-feats)
      const int fo = nh * 64;
#pragma unroll
      for (int ks = 0; ks < 4; ++ks) {
        bs8 Ah[2], Bw[4];
#pragma unroll
        for (int rt = 0; rt < 2; ++rt)
          Ah[rt] = *(const bs8*)(&h1S[mh * 32 + rt * 16 + l15][ks * 32 + lg * 8]);
#pragma unroll
        for (int ct = 0; ct < 4; ++ct)
          Bw[ct] = *(const bs8*)(W2T + (fo + ct * 16 + l15) * 256 + c * 128 + ks * 32 + lg * 8);
#pragma unroll
        for (int ct = 0; ct < 4; ++ct)
#pragma unroll
          for (int rt = 0; rt < 2; ++rt)
            accL2[ct][rt] = MFMA16(Ah[rt], Bw[ct], accL2[ct][rt], 0, 0, 0);
      }
    }
    __syncthreads();  // done reading h1 chunk before overwrite
  }

  {  // L2 epilogue: pk gelu + mask + per-q row-sum -> h2b (h0S rows 0..3) bf16
    const int fo = nh * 64;
    float psum[4];
#pragma unroll
    for (int ct = 0; ct < 4; ++ct) {
      float bias = b2[fo + ct * 16 + l15];
      float s = 0.0f;
#pragma unroll
      for (int rt = 0; rt < 2; ++rt) {
        f2 u0 = {accL2[ct][rt][0] + bias, accL2[ct][rt][1] + bias};
        f2 u1 = {accL2[ct][rt][2] + bias, accL2[ct][rt][3] + bias};
        f2 gA = gelu2(u0);
        f2 gB = gelu2(u1);
        int row = mh * 32 + rt * 16 + lg * 4;
        s += gA.x * maskfS[row] + gA.y * maskfS[row + 1] +
             gB.x * maskfS[row + 2] + gB.y * maskfS[row + 3];
      }
      psum[ct] = s;
    }
#pragma unroll
    for (int ct = 0; ct < 4; ++ct) {
      psum[ct] += __shfl_xor(psum[ct], 16, 64);
      psum[ct] += __shfl_xor(psum[ct], 32, 64);
    }
    if (lane < 16) {
#pragma unroll
      for (int ct = 0; ct < 4; ++ct)
        h0S[mh][fo + ct * 16 + lane] = f2bf(psum[ct]);
    }
  }
  __syncthreads();  // h2b ready (rows 0..3; rows 4..15 stale h0 = finite)
  {  // fused W3: out = h2b @ W3 + cnt*b3, direct transposed store
    const int wf = wid * 16;
    f4 a3 = {};
#pragma unroll
    for (int ks = 0; ks < 4; ++ks) {
      bs8 Ah = *(const bs8*)(&h0S[l15][ks * 32 + lg * 8]);
      bs8 Bw = *(const bs8*)(W3T + (wf + l15) * 128 + ks * 32 + lg * 8);
      a3 = MFMA16(Ah, Bw, a3, 0, 0, 0);
    }
    if (lg == 0) {
      int feat = wf + l15;
      float bb3 = b3S[feat];
#pragma unroll
      for (int i = 0; i < 4; ++i) {
        int q = q0 + i;
        out[(b << 19) + (feat << 12) + ((q & 15) << 8) + ((q >> 8) << 4) +
            ((q >> 4) & 15)] = a3[i] + cntS[i] * bb3;
      }
    }
  }
}

// =================== old (fallback) path — round-1 kernels ===================

__global__ void gno_prep(const float* __restrict__ W0, const float* __restrict__ W1,
                         const float* __restrict__ W2, const float* __restrict__ W3,
                         short* __restrict__ W0aT, short* __restrict__ W1T,
                         short* __restrict__ W2T, short* __restrict__ W3T) {
  int g = blockIdx.x * 256 + threadIdx.x;
  if (g < 16384) {
    int n = g >> 7, k = g & 127;
    float v = (k < 96) ? W0[k * 128 + n] : ((k < 100) ? W0[(k + 96) * 128 + n] : 0.0f);
    W0aT[g] = f2bf(v);
  } else if (g < 49152) {
    int h = g - 16384, n = h >> 7, k = h & 127;
    W1T[h] = f2bf(W1[k * 256 + n]);
  } else if (g < 81920) {
    int h = g - 49152, n = h >> 8, k = h & 255;
    W2T[h] = f2bf(W2[k * 128 + n]);
  } else if (g < 98304) {
    int h = g - 81920, n = h >> 7, k = h & 127;
    W3T[h] = f2bf(W3[k * 128 + n]);
  }
}

template <int SIN, int K>
__device__ __forceinline__ void gemm_block(const short* inS, const short* __restrict__ WT,
                                           int colBase, int lane, f4 (&acc)[2][4]) {
  constexpr int KS = K / 32;
  bs8 Bf[2][KS];
  const int bcol = lane & 15;
  const int bk = (lane >> 4) * 8;
#pragma unroll
  for (int ct = 0; ct < 2; ++ct)
#pragma unroll
    for (int ks = 0; ks < KS; ++ks)
      Bf[ct][ks] = *reinterpret_cast<const bs8*>(WT + (colBase + ct * 16 + bcol) * K + ks * 32 + bk);
#pragma unroll
  for (int mt = 0; mt < 4; ++mt) {
#pragma unroll
    for (int ks = 0; ks < KS; ++ks) {
      bs8 Af = *reinterpret_cast<const bs8*>(inS + (mt * 16 + bcol) * SIN + ks * 32 + bk);
      acc[0][mt] = MFMA16(Af, Bf[0][ks], acc[0][mt], 0, 0, 0);
      acc[1][mt] = MFMA16(Af, Bf[1][ks], acc[1][mt], 0, 0, 0);
    }
  }
}

__global__ __launch_bounds__(256, 2) void gno_main(
    const float* __restrict__ x, const float* __restrict__ gc,
    const float* __restrict__ latg, const int* __restrict__ nidx,
    const float* __restrict__ W0, const float* __restrict__ b0,
    const float* __restrict__ b1, const float* __restrict__ b2,
    const float* __restrict__ b3,
    const short* __restrict__ W0aT, const short* __restrict__ W1T,
    const short* __restrict__ W2T, const short* __restrict__ W3T,
    float* __restrict__ dst, int direct) {
  __shared__ __align__(16) short aggS[64][136];
  __shared__ __align__(16) short h0S[64][136];
  __shared__ __align__(16) short h1S[64][264];
  __shared__ float vqS[2][128];
  __shared__ float maskfS[64];
  __shared__ float freqS[16];
  __shared__ float latS[2][3];
  __shared__ float sEmbQ[2][96];

  const int tid = threadIdx.x;
  const int blk = blockIdx.x;
  const int b = blk >> 11;
  const int q0 = (blk & 2047) * 2;

  if (tid < 16) freqS[tid] = (float)exp(-(double)tid * (9.210340371976184 / 16.0));
  if (tid >= 32 && tid < 38) {
    int t = tid - 32, qh = t / 3, a = t % 3;
    latS[qh][a] = latg[(q0 + qh) * 3 + a];
  }
  __syncthreads();
  if (tid < 192) {
    int qh = tid / 96, c = tid % 96, a = c >> 5, jj = c & 31;
    float ca = latS[qh][a];
    sEmbQ[qh][c] = (jj < 16) ? __sinf(ca * freqS[jj]) : __cosf(ca * freqS[jj & 15]);
  }
  __syncthreads();
  {
    int qh = tid >> 7, o = tid & 127;
    float s = b0[o];
#pragma unroll 4
    for (int j = 0; j < 96; ++j) s = fmaf(sEmbQ[qh][j], W0[(96 + j) * 128 + o], s);
    vqS[qh][o] = s;
  }
  {
    int r = tid >> 2, qq = tid & 3;
    int qh = r >> 5, kk = r & 31;
    int n = nidx[(q0 + qh) * 32 + kk];
    float c0 = gc[n * 3], c1 = gc[n * 3 + 1], c2 = gc[n * 3 + 2];
    if (qq == 0) {
      float d0 = __fsub_rn(latS[qh][0], c0);
      float d1 = __fsub_rn(latS[qh][1], c1);
      float d2 = __fsub_rn(latS[qh][2], c2);
      float s = __fadd_rn(__fadd_rn(__fmul_rn(d0, d0), __fmul_rn(d1, d1)), __fmul_rn(d2, d2));
      maskfS[r] = ((double)s <= 0.055 * 0.055) ? 1.0f : 0.0f;
    }
    float cc[3] = {c0, c1, c2};
    for (int c = qq * 34; c < qq * 34 + 34; ++c) {
      float v = 0.0f;
      if (c < 96) {
        int a = c >> 5, jj = c & 31;
        v = (jj < 16) ? __sinf(cc[a] * freqS[jj]) : __cosf(cc[a] * freqS[jj & 15]);
      } else if (c < 100) {
        int ch = c - 96;
        v = x[((b * 4 + ch) << 15) + ((n & 31) << 10) + (n >> 5)];
      }
      aggS[r][c] = f2bf(v);
    }
  }
  __syncthreads();

  const int wave = tid >> 6, lane = tid & 63;
  const int colBase = wave * 32;
  const int lrow4 = (lane >> 4) << 2;
  const int lcol = lane & 15;

  {
    f4 acc[2][4] = {};
    gemm_block<136, 128>(&aggS[0][0], W0aT, colBase, lane, acc);
#pragma unroll
    for (int ct = 0; ct < 2; ++ct) {
      int gcol = colBase + ct * 16 + lcol;
#pragma unroll
      for (int mt = 0; mt < 4; ++mt)
#pragma unroll
        for (int i = 0; i < 4; ++i) {
          int grow = mt * 16 + lrow4 + i;
          h0S[grow][gcol] = f2bf(gelu_old(acc[ct][mt][i] + vqS[grow >> 5][gcol]));
        }
    }
  }
  __syncthreads();
  {
#pragma unroll 1
    for (int cg = 0; cg < 2; ++cg) {
      int cb = wave * 64 + cg * 32;
      f4 acc[2][4] = {};
      gemm_block<136, 128>(&h0S[0][0], W1T, cb, lane, acc);
#pragma unroll
      for (int ct = 0; ct < 2; ++ct) {
        int gcol = cb + ct * 16 + lcol;
        float bias = b1[gcol];
#pragma unroll
        for (int mt = 0; mt < 4; ++mt)
#pragma unroll
          for (int i = 0; i < 4; ++i) {
            int grow = mt * 16 + lrow4 + i;
            h1S[grow][gcol] = f2bf(gelu_old(acc[ct][mt][i] + bias));
          }
      }
    }
  }
  __syncthreads();
  {
    f4 acc[2][4] = {};
    gemm_block<264, 256>(&h1S[0][0], W2T, colBase, lane, acc);
#pragma unroll
    for (int ct = 0; ct < 2; ++ct) {
      int gcol = colBase + ct * 16 + lcol;
      float bias = b2[gcol];
#pragma unroll
      for (int mt = 0; mt < 4; ++mt)
#pragma unroll
        for (int i = 0; i < 4; ++i) {
          int grow = mt * 16 + lrow4 + i;
          aggS[grow][gcol] = f2bf(gelu_old(acc[ct][mt][i] + bias));
        }
    }
  }
  __syncthreads();
  {
    f4 acc[2][4] = {};
    gemm_block<136, 128>(&aggS[0][0], W3T, colBase, lane, acc);
    float part[2][2] = {{0.0f, 0.0f}, {0.0f, 0.0f}};
#pragma unroll
    for (int ct = 0; ct < 2; ++ct) {
      float bias = b3[colBase + ct * 16 + lcol];
#pragma unroll
      for (int mt = 0; mt < 4; ++mt)
#pragma unroll
        for (int i = 0; i < 4; ++i) {
          int grow = mt * 16 + lrow4 + i;
          part[mt >> 1][ct] += (acc[ct][mt][i] + bias) * maskfS[grow];
        }
    }
#pragma unroll
    for (int qh = 0; qh < 2; ++qh)
#pragma unroll
      for (int ct = 0; ct < 2; ++ct) {
        float v = part[qh][ct];
        v += __shfl_xor(v, 16, 64);
        v += __shfl_xor(v, 32, 64);
        if (lane < 16) {
          int o = colBase + ct * 16 + lane;
          int q = q0 + qh;
          if (direct)
            dst[(b << 19) + (o << 12) + ((q & 15) << 8) + ((q >> 8) << 4) + ((q >> 4) & 15)] = v;
          else
            dst[(b * 4096 + q) * 128 + o] = v;
        }
      }
  }
}

__global__ void gno_tr(const float* __restrict__ staged, float* __restrict__ out) {
  __shared__ float tile[16][129];
  int blk = blockIdx.x;
  int b = blk >> 8, i = (blk >> 4) & 15, l = blk & 15;
  int t = threadIdx.x;
  {
    int j = t >> 4, oc = t & 15;
    const float* src = staged + ((b * 4096) + (i * 256 + j * 16 + l)) * 128 + oc * 8;
#pragma unroll
    for (int u = 0; u < 8; ++u) tile[j][oc * 8 + u] = src[u];
  }
  __syncthreads();
  {
    int og = t >> 4, j = t & 15;
#pragma unroll
    for (int oo = 0; oo < 8; ++oo) {
      int o = og * 8 + oo;
      out[(b << 19) + (o << 12) + (l << 8) + (i << 4) + j] = tile[j][o];
    }
  }
}

extern "C" void kernel_launch(void* const* d_in, const int* in_sizes, int n_in,
                              void* d_out, int out_size, void* d_ws, size_t ws_size,
                              hipStream_t stream) {
  const float* x    = (const float*)d_in[0];
  const float* gc   = (const float*)d_in[1];
  const float* latg = (const float*)d_in[2];
  const int*   nidx = (const int*)d_in[3];
  const float* W0 = (const float*)d_in[5];
  const float* b0 = (const float*)d_in[6];
  const float* W1 = (const float*)d_in[7];
  const float* b1 = (const float*)d_in[8];
  const float* W2 = (const float*)d_in[9];
  const float* b2 = (const float*)d_in[10];
  const float* W3 = (const float*)d_in[11];
  const float* b3 = (const float*)d_in[12];

  char* ws = (char*)d_ws;
  float* out = (float*)d_out;

  if (ws_size >= (size_t)FAST_NEED) {
    short* W1T  = (short*)(ws + W1T_OFF);
    short* W2T  = (short*)(ws + W2T_OFF);
    short* W3T  = (short*)(ws + W3T_OFF);
    short* W0eT = (short*)(ws + W0ET_OFF);
    short* W0mT = (short*)(ws + W0MT_OFF);
    gno_prep4<<<416, 256, 0, stream>>>(W0, W1, W2, W3, W1T, W2T, W3T, W0eT, W0mT);
    gno_main8<<<2048, 512, 0, stream>>>(nidx, x, gc, latg, W0, b0, b1, b2, b3,
                                        W0eT, W0mT, W1T, W2T, W3T, out);
  } else {
    short* W0aT = (short*)(ws + OW0AT_OFF);
    short* W1T  = (short*)(ws + OW1T_OFF);
    short* W2T  = (short*)(ws + OW2T_OFF);
    short* W3T  = (short*)(ws + OW3T_OFF);
    float* staged = (float*)(ws + OSTAGED_OFF);
    const bool use_staged = (ws_size >= (size_t)OLD_NEED);
    gno_prep<<<384, 256, 0, stream>>>(W0, W1, W2, W3, W0aT, W1T, W2T, W3T);
    gno_main<<<4096, 256, 0, stream>>>(x, gc, latg, nidx, W0, b0, b1, b2, b3,
                                       W0aT, W1T, W2T, W3T,
                                       use_staged ? staged : out, use_staged ? 0 : 1);
    if (use_staged) gno_tr<<<512, 256, 0, stream>>>(staged, out);
  }
}